// Round 14
// baseline (265.611 us; speedup 1.0000x reference)
//
#include <hip/hip_runtime.h>
#include <stdint.h>

#define LSEQ 1024
#define HDIM 1024
#define DDIM 2048
#define BL 2048
#define NST 16
#define XR 1027          // 3 halo rows (zeroed in k_prep) + 1024 tokens

typedef unsigned short u16;
typedef __attribute__((ext_vector_type(8))) short bf16x8;
typedef __attribute__((ext_vector_type(4))) float f32x4;

// silu via v_rcp (1-ulp rcp; output tolerance is bf16-dominated)
static __device__ __forceinline__ float silu_f(float v) {
  return v * __builtin_amdgcn_rcpf(1.f + __expf(-v));
}
static __device__ __forceinline__ float bf2f(u16 u) {
  union { float f; unsigned int i; } c; c.i = ((unsigned int)u) << 16; return c.f;
}
static __device__ __forceinline__ u16 f2bf(float f) {
  union { float f; unsigned int i; } c; c.f = f;
  unsigned int r = c.i + 0x7fffu + ((c.i >> 16) & 1u);
  return (u16)(r >> 16);
}
static __device__ __forceinline__ float softplus_f(float v) {
  return (v > 20.f) ? v : __logf(1.f + __expf(v));
}

// ---------------- fused prep: castw(w1), castw(wo), castsplit(xpw), zerohalo, rmsnorm ----
__global__ __launch_bounds__(256) void k_prep(const float* __restrict__ w1,
                                              u16* __restrict__ w1b,
                                              const float* __restrict__ wo,
                                              u16* __restrict__ wob,
                                              const float* __restrict__ xpw,
                                              u16* __restrict__ whb,
                                              u16* __restrict__ wlb,
                                              u16* __restrict__ xgb,
                                              const float* __restrict__ inp,
                                              const float* __restrict__ nw,
                                              u16* __restrict__ xnb) {
  int bidx = blockIdx.x;
  int t = threadIdx.x;
  if (bidx < 4096) {
    int idx = bidx * 256 + t;
    float4 v = ((const float4*)w1)[idx];
    ushort4 o;
    o.x = f2bf(v.x); o.y = f2bf(v.y); o.z = f2bf(v.z); o.w = f2bf(v.w);
    ((ushort4*)w1b)[idx] = o;
  } else if (bidx < 6144) {
    int idx = (bidx - 4096) * 256 + t;
    float4 v = ((const float4*)wo)[idx];
    ushort4 o;
    o.x = f2bf(v.x); o.y = f2bf(v.y); o.z = f2bf(v.z); o.w = f2bf(v.w);
    ((ushort4*)wob)[idx] = o;
  } else if (bidx < 6336) {
    int idx = (bidx - 6144) * 256 + t;
    float4 v = ((const float4*)xpw)[idx];
    ushort4 h, l;
    h.x = f2bf(v.x); l.x = f2bf(v.x - bf2f(h.x));
    h.y = f2bf(v.y); l.y = f2bf(v.y - bf2f(h.y));
    h.z = f2bf(v.z); l.z = f2bf(v.z - bf2f(h.z));
    h.w = f2bf(v.w); l.w = f2bf(v.w - bf2f(h.w));
    ((ushort4*)whb)[idx] = h;
    ((ushort4*)wlb)[idx] = l;
  } else if (bidx < 6360) {
    int idx = (bidx - 6336) * 256 + t;      // 6144 ushort4: 2 b x 3 rows x 1024
    int b = idx / 3072;
    int r = idx - b * 3072;
    ushort4 z4 = {0, 0, 0, 0};
    ((ushort4*)(xgb + (size_t)b * XR * 4096))[r] = z4;
  } else {
    // rmsnorm + normalize -> xnb bf16 [2048][1024]
    int row = bidx - 6360;
    float4 xv = *(const float4*)(inp + (size_t)row * HDIM + t * 4);
    float ss = xv.x * xv.x + xv.y * xv.y + xv.z * xv.z + xv.w * xv.w;
    for (int off = 32; off > 0; off >>= 1) ss += __shfl_down(ss, off);
    __shared__ float red[4];
    if ((t & 63) == 0) red[t >> 6] = ss;
    __syncthreads();
    float tot = red[0] + red[1] + red[2] + red[3];
    float scale = rsqrtf(tot * (1.f / HDIM) + 1e-6f);
    float4 nv = *(const float4*)(nw + t * 4);
    ushort4 o;
    o.x = f2bf(xv.x * scale * nv.x); o.y = f2bf(xv.y * scale * nv.y);
    o.z = f2bf(xv.z * scale * nv.z); o.w = f2bf(xv.w * scale * nv.w);
    ((ushort4*)xnb)[row * 256 + t] = o;
  }
}

// ---------------- K1: in_proj GEMM, 128x128 tile, pure bf16 ----------------
__global__ __launch_bounds__(256) void k_gemm1b(const u16* __restrict__ A,
                                                const u16* __restrict__ W,
                                                const float* __restrict__ bias,
                                                u16* __restrict__ xgb) {
  __shared__ u16 Asm[128 * 40];
  __shared__ u16 Wsm[128 * 40];
  int t = threadIdx.x;
  int m0 = blockIdx.y * 128, n0 = blockIdx.x * 128;
  int srow = t >> 1, koff = (t & 1) * 16;
  const u16* Ag = A + (size_t)(m0 + srow) * HDIM + koff;
  const u16* Wg = W + (size_t)(n0 + srow) * HDIM + koff;
  int w = t >> 6, lane = t & 63;
  int wr = w >> 1, wc = w & 1;
  int quad = lane >> 4, mr = lane & 15;
  f32x4 z = {0.f, 0.f, 0.f, 0.f};
  f32x4 acc[4][4] = {{z, z, z, z}, {z, z, z, z}, {z, z, z, z}, {z, z, z, z}};
  const u16* arp = &Asm[(wr * 64 + mr) * 40 + quad * 8];
  const u16* brp = &Wsm[(wc * 64 + mr) * 40 + quad * 8];
  for (int k0 = 0; k0 < HDIM; k0 += 32) {
    uint4 a0 = *(const uint4*)(Ag + k0);
    uint4 a1 = *(const uint4*)(Ag + k0 + 8);
    uint4 w0 = *(const uint4*)(Wg + k0);
    uint4 w1 = *(const uint4*)(Wg + k0 + 8);
    __syncthreads();
    *(uint4*)(&Asm[srow * 40 + koff]) = a0;
    *(uint4*)(&Asm[srow * 40 + koff + 8]) = a1;
    *(uint4*)(&Wsm[srow * 40 + koff]) = w0;
    *(uint4*)(&Wsm[srow * 40 + koff + 8]) = w1;
    __syncthreads();
    bf16x8 af[4], bf[4];
#pragma unroll
    for (int i = 0; i < 4; i++) {
      af[i] = *(const bf16x8*)(arp + i * 16 * 40);
      bf[i] = *(const bf16x8*)(brp + i * 16 * 40);
    }
#pragma unroll
    for (int mi = 0; mi < 4; mi++)
#pragma unroll
      for (int ni = 0; ni < 4; ni++)
        acc[mi][ni] = __builtin_amdgcn_mfma_f32_16x16x32_bf16(af[mi], bf[ni],
                                                              acc[mi][ni], 0, 0, 0);
  }
#pragma unroll
  for (int ni = 0; ni < 4; ni++) {
    int col = n0 + wc * 64 + ni * 16 + mr;
    float bv = bias[col];
#pragma unroll
    for (int mi = 0; mi < 4; mi++) {
#pragma unroll
      for (int rr2 = 0; rr2 < 4; rr2++) {
        int rr = m0 + wr * 64 + mi * 16 + quad * 4 + rr2;
        int row = (rr >> 10) * XR + 3 + (rr & 1023);
        xgb[(size_t)row * 4096 + col] = f2bf(acc[mi][ni][rr2] + bv);
      }
    }
  }
}

// ---------------- K1b: transpose x-half of xgb -> xT[2048 d][2048 tok] (bf16) ----------------
__global__ __launch_bounds__(256) void k_xT(const u16* __restrict__ xgb,
                                            u16* __restrict__ xT) {
  __shared__ u16 tile[64][66];      // row stride 66 u16 = 33 dwords (odd -> conflict-free cols)
  int dt = blockIdx.x & 31;         // d-tile (64 d)
  int tt = blockIdx.x >> 5;         // tok-tile (64 tok)
  int gtok0 = tt << 6;
  int b = gtok0 >> 10, l0 = gtok0 & 1023;
  int d0 = dt << 6;
  int t = threadIdx.x;
  const u16* src = xgb + (size_t)(b * XR + 3 + l0) * 4096 + d0;
#pragma unroll
  for (int i = 0; i < 8; i++) {
    int idx = t + i * 256;          // 0..2047
    int row = idx >> 5, uc = idx & 31;
    unsigned int v = *(const unsigned int*)(src + (size_t)row * 4096 + uc * 2);
    tile[row][uc * 2]     = (u16)(v & 0xffffu);
    tile[row][uc * 2 + 1] = (u16)(v >> 16);
  }
  __syncthreads();
#pragma unroll
  for (int i = 0; i < 8; i++) {
    int idx = t + i * 256;
    int r = idx >> 5, c2 = idx & 31;          // d-row r, token pair c2
    unsigned int lo = tile[c2 * 2][r];
    unsigned int hi = tile[c2 * 2 + 1][r];
    *(unsigned int*)(xT + (size_t)(d0 + r) * 2048 + gtok0 + c2 * 2) = lo | (hi << 16);
  }
}

// ---------------- K4: out_proj GEMM, 128x64 tile, split-K x2 -> f32 partials ----------------
__global__ __launch_bounds__(256) void k_gemm2b(const u16* __restrict__ A,
                                                const u16* __restrict__ W,
                                                float* __restrict__ psplit) {
  __shared__ u16 Asm[128 * 40];
  __shared__ u16 Wsm[64 * 40];
  int t = threadIdx.x;
  int m0 = blockIdx.y * 128, n0 = blockIdx.x * 64;
  int kstart = blockIdx.z << 10;
  float* outp = psplit + (size_t)blockIdx.z * 2048 * 1024;
  int srow = t >> 1, koff = (t & 1) * 16;
  const u16* Ag = A + (size_t)(m0 + srow) * DDIM + kstart + koff;
  const u16* Wg = W + (size_t)(n0 + (srow & 63)) * DDIM + kstart + koff;
  int w = t >> 6, lane = t & 63;
  int wr = w >> 1, wc = w & 1;
  int quad = lane >> 4, mr = lane & 15;
  f32x4 z = {0.f, 0.f, 0.f, 0.f};
  f32x4 acc[4][2] = {{z, z}, {z, z}, {z, z}, {z, z}};
  const u16* arp = &Asm[(wr * 64 + mr) * 40 + quad * 8];
  const u16* brp = &Wsm[(wc * 32 + mr) * 40 + quad * 8];
  for (int k0 = 0; k0 < 1024; k0 += 32) {
    uint4 a0 = *(const uint4*)(Ag + k0);
    uint4 a1 = *(const uint4*)(Ag + k0 + 8);
    uint4 w0, w1;
    if (t < 128) {
      w0 = *(const uint4*)(Wg + k0);
      w1 = *(const uint4*)(Wg + k0 + 8);
    }
    __syncthreads();
    *(uint4*)(&Asm[srow * 40 + koff]) = a0;
    *(uint4*)(&Asm[srow * 40 + koff + 8]) = a1;
    if (t < 128) {
      *(uint4*)(&Wsm[srow * 40 + koff]) = w0;
      *(uint4*)(&Wsm[srow * 40 + koff + 8]) = w1;
    }
    __syncthreads();
    bf16x8 af[4], bf[2];
#pragma unroll
    for (int i = 0; i < 4; i++) af[i] = *(const bf16x8*)(arp + i * 16 * 40);
#pragma unroll
    for (int i = 0; i < 2; i++) bf[i] = *(const bf16x8*)(brp + i * 16 * 40);
#pragma unroll
    for (int mi = 0; mi < 4; mi++)
#pragma unroll
      for (int ni = 0; ni < 2; ni++)
        acc[mi][ni] = __builtin_amdgcn_mfma_f32_16x16x32_bf16(af[mi], bf[ni],
                                                              acc[mi][ni], 0, 0, 0);
  }
#pragma unroll
  for (int ni = 0; ni < 2; ni++) {
    int col = n0 + wc * 32 + ni * 16 + mr;
#pragma unroll
    for (int mi = 0; mi < 4; mi++) {
#pragma unroll
      for (int rr2 = 0; rr2 < 4; rr2++) {
        int row = m0 + wr * 64 + mi * 16 + quad * 4 + rr2;
        outp[(size_t)row * 1024 + col] = acc[mi][ni][rr2];
      }
    }
  }
}

// ---------------- K4b: combine split-K partials + bias + residual -> out ----------------
__global__ __launch_bounds__(256) void k_ocomb(const float* __restrict__ psplit,
                                               const float* __restrict__ bias,
                                               const float* __restrict__ resid,
                                               float* __restrict__ out) {
  int idx = blockIdx.x * 256 + threadIdx.x;   // float4 over [2048][1024]
  int colf = idx & 255;
  float4 a = ((const float4*)psplit)[idx];
  float4 b2 = ((const float4*)(psplit + 2048 * 1024))[idx];
  float4 rv = ((const float4*)resid)[idx];
  float4 bv = *(const float4*)(bias + colf * 4);
  float4 o;
  o.x = a.x + b2.x + bv.x + rv.x;
  o.y = a.y + b2.y + bv.y + rv.y;
  o.z = a.z + b2.z + bv.z + rv.z;
  o.w = a.w + b2.w + bv.w + rv.w;
  ((float4*)out)[idx] = o;
}

// ---------------- K2 v3: fused conv+silu + x_proj GEMM -> projT, 16 K-partitions ----
__global__ __launch_bounds__(256) void k_xprojT(const u16* __restrict__ xgb,
                                                const u16* __restrict__ whb,
                                                const u16* __restrict__ wlb,
                                                const float* __restrict__ cw,
                                                const float* __restrict__ cb,
                                                float* __restrict__ projT,
                                                float* __restrict__ pscr) {
  __shared__ u16 Xst[67 * 40];
  __shared__ u16 XH[64 * 40];
  __shared__ u16 XL[64 * 40];
  __shared__ u16 WH[96 * 40];
  __shared__ u16 WL[96 * 40];
  int t = threadIdx.x;
  int tt = blockIdx.x & 31, ks = blockIdx.x >> 5;
  int tokbase = tt << 6;
  int b = tokbase >> 10, l0 = tokbase & 1023;
  int kbase = ks << 7;
  const u16* xbase = xgb + (size_t)(b * XR + l0) * 4096;
  float* outp = (ks == 0) ? projT : (pscr + (size_t)(ks - 1) * 196608);
  int dlane = t & 31, tokg = t >> 5;
  int wvq = t >> 6, lane = t & 63;
  int quad = lane >> 4, mr = lane & 15;
  f32x4 z = {0.f, 0.f, 0.f, 0.f};
  f32x4 acc[6] = {z, z, z, z, z, z};

  for (int it = 0; it < 4; it++) {
    int kc = kbase + (it << 5);
    for (int idx = t; idx < 268; idx += 256) {
      int r = idx >> 2, p = idx & 3;
      uint4 v = *(const uint4*)(xbase + (size_t)r * 4096 + kc + p * 8);
      *(uint4*)(&Xst[r * 40 + p * 8]) = v;
    }
    for (int idx = t; idx < 384; idx += 256) {
      int r = idx >> 2, p = idx & 3;
      *(uint4*)(&WH[r * 40 + p * 8]) = *(const uint4*)(whb + (size_t)r * 2048 + kc + p * 8);
      *(uint4*)(&WL[r * 40 + p * 8]) = *(const uint4*)(wlb + (size_t)r * 2048 + kc + p * 8);
    }
    __syncthreads();
    {
      int d = kc + dlane;
      float4 cwv = *(const float4*)(cw + d * 4);
      float cbv = cb[d];
      float xr[11];
#pragma unroll
      for (int j = 0; j < 11; j++) xr[j] = bf2f(Xst[(tokg * 8 + j) * 40 + dlane]);
#pragma unroll
      for (int jj = 0; jj < 8; jj++) {
        float xc = silu_f(cbv + cwv.x * xr[jj] + cwv.y * xr[jj + 1] +
                          cwv.z * xr[jj + 2] + cwv.w * xr[jj + 3]);
        u16 h = f2bf(xc);
        u16 l = f2bf(xc - bf2f(h));
        XH[(tokg * 8 + jj) * 40 + dlane] = h;
        XL[(tokg * 8 + jj) * 40 + dlane] = l;
      }
    }
    __syncthreads();
    bf16x8 xh = *(const bf16x8*)(&XH[(wvq * 16 + mr) * 40 + quad * 8]);
    bf16x8 xl = *(const bf16x8*)(&XL[(wvq * 16 + mr) * 40 + quad * 8]);
#pragma unroll
    for (int mi = 0; mi < 6; mi++) {
      bf16x8 wh = *(const bf16x8*)(&WH[(mi * 16 + mr) * 40 + quad * 8]);
      bf16x8 wl = *(const bf16x8*)(&WL[(mi * 16 + mr) * 40 + quad * 8]);
      acc[mi] = __builtin_amdgcn_mfma_f32_16x16x32_bf16(wh, xh, acc[mi], 0, 0, 0);
      acc[mi] = __builtin_amdgcn_mfma_f32_16x16x32_bf16(wh, xl, acc[mi], 0, 0, 0);
      acc[mi] = __builtin_amdgcn_mfma_f32_16x16x32_bf16(wl, xh, acc[mi], 0, 0, 0);
    }
    __syncthreads();
  }
#pragma unroll
  for (int mi = 0; mi < 6; mi++) {
#pragma unroll
    for (int rr = 0; rr < 4; rr++) {
      int o = mi * 16 + quad * 4 + rr;
      outp[(size_t)o * BL + tokbase + wvq * 16 + mr] = acc[mi][rr];
    }
  }
}

// ---------------- K2d: combine 16 K-partials + bias into projT ----------------
__global__ __launch_bounds__(256) void k_xcomb(float* __restrict__ projT,
                                               const float* __restrict__ scr,
                                               const float* __restrict__ xpb) {
  int idx = blockIdx.x * 256 + threadIdx.x;
  int o = idx >> 9;
  float4 a = ((const float4*)projT)[idx];
  float bv = xpb[o];
  float sx = bv, sy = bv, sz = bv, sw = bv;
#pragma unroll
  for (int p = 0; p < 15; p++) {
    float4 s = ((const float4*)(scr + (size_t)p * 196608))[idx];
    sx += s.x; sy += s.y; sz += s.z; sw += s.w;
  }
  a.x += sx; a.y += sy; a.z += sz; a.w += sw;
  ((float4*)projT)[idx] = a;
}

// ---------------- K2c: delta GEMM: deltaT[2048 d][2048 tok] = softplus(dtw.projT + dtb) ----
__global__ __launch_bounds__(256) void k_delta(const float* __restrict__ projT,
                                               const float* __restrict__ dtw,
                                               const float* __restrict__ dtb,
                                               float* __restrict__ deltaT) {
  __shared__ float dw_s[16][64];
  int t = threadIdx.x;
  int d0 = (blockIdx.x >> 3) * 16;
  int tokbase = (blockIdx.x & 7) * 256;
  {
    const float* src = dtw + (size_t)d0 * 64;
#pragma unroll
    for (int i = 0; i < 4; i++) {
      int idx = t + i * 256;
      dw_s[idx >> 6][idx & 63] = src[idx];
    }
  }
  __syncthreads();
  int tq = t & 63, dq = t >> 6;
  const float* pr = projT + tokbase + tq * 4;
  int dbase = d0 + dq * 4;
  float acc[4][4];
#pragma unroll
  for (int di = 0; di < 4; di++) {
    float bv = dtb[dbase + di];
    acc[di][0] = bv; acc[di][1] = bv; acc[di][2] = bv; acc[di][3] = bv;
  }
#pragma unroll 8
  for (int r = 0; r < 64; r++) {
    float4 pv = *(const float4*)(pr + (size_t)r * BL);
#pragma unroll
    for (int di = 0; di < 4; di++) {
      float wk = dw_s[dq * 4 + di][r];
      acc[di][0] += pv.x * wk; acc[di][1] += pv.y * wk;
      acc[di][2] += pv.z * wk; acc[di][3] += pv.w * wk;
    }
  }
#pragma unroll
  for (int di = 0; di < 4; di++) {
    float4 o;
    o.x = softplus_f(acc[di][0]); o.y = softplus_f(acc[di][1]);
    o.z = softplus_f(acc[di][2]); o.w = softplus_f(acc[di][3]);
    *(float4*)(deltaT + (size_t)(dbase + di) * BL + tokbase + tq * 4) = o;
  }
}

// ---------------- K3 v5: selective scan, fully coalesced, single C pass ----------------
// pcv[i] = Pp*Cv saved in phase 1 (16 VGPR) -> phase 2 is y[i] += Soff*pcv[i]:
// no C reload, no exp recompute.  (Regroups (Soff*Pp)*Cv -> Soff*(Pp*Cv),
// <=1 ulp f32 pre-gating.)  Un-gated y (f32) written into own deltaT slice;
// k_gate does gating+transpose.
__global__ __launch_bounds__(256) void k_scan2(const float* __restrict__ projT,
                                               float* __restrict__ deltaT,
                                               const u16* __restrict__ xT,
                                               const float* __restrict__ cw,
                                               const float* __restrict__ cb,
                                               const float* __restrict__ alog,
                                               const float* __restrict__ dparam,
                                               const float* __restrict__ cs) {
  __shared__ float wtot[4];
  __shared__ float xcp[1088];
  __shared__ float uvl[1088];
  __shared__ float dlp[1088];

  int t = threadIdx.x;
  int cidx = ((blockIdx.x & 7) << 9) | (blockIdx.x >> 3);   // (b,d)
  int b = cidx >> 11;
  int d = cidx & (DDIM - 1);
  int wv = t >> 6, lane = t & 63;

  float4 cwv = *(const float4*)(cw + d * 4);
  float cbv = cb[d];
  float Dp = dparam[d];
  int colbase = b << 10;
  int tok0 = t << 2;
  float* drow = deltaT + (size_t)d * BL + colbase;

  float4 dv = *(const float4*)(drow + tok0);

  // ---- stage x row (coalesced from xT) into dlp-aliased xls ----
  float* xls = dlp;
  if (t < 3) xls[t] = 0.f;
  {
    ushort4 xv = ((const ushort4*)(xT + (size_t)d * 2048 + colbase))[t];
    xls[3 + tok0 + 0] = bf2f(xv.x);
    xls[3 + tok0 + 1] = bf2f(xv.y);
    xls[3 + tok0 + 2] = bf2f(xv.z);
    xls[3 + tok0 + 3] = bf2f(xv.w);
  }
  __syncthreads();                       // B1

#pragma unroll
  for (int i = 0; i < 4; i++) {
    int tok = tok0 + i;
    float xc = silu_f(cbv + cwv.x * xls[tok] + cwv.y * xls[tok + 1] +
                      cwv.z * xls[tok + 2] + cwv.w * xls[tok + 3]);
    xcp[((tok >> 4) * 17) + (tok & 15)] = xc;
  }
  float d0 = dv.x, d1 = dv.y, d2 = dv.z, d3 = dv.w;
  uvl[((tok0 >> 4) * 17) + (tok0 & 15)]             = d0;
  uvl[(((tok0 + 1) >> 4) * 17) + ((tok0 + 1) & 15)] = d1;
  uvl[(((tok0 + 2) >> 4) * 17) + ((tok0 + 2) & 15)] = d2;
  uvl[(((tok0 + 3) >> 4) * 17) + ((tok0 + 3) & 15)] = d3;
  float c0 = d0, c1 = c0 + d1, c2 = c1 + d2, c3 = c2 + d3;
  float sc = c3;
#pragma unroll
  for (int off = 1; off < 64; off <<= 1) {
    float u = __shfl_up(sc, off);
    if (lane >= off) sc += u;
  }
  if (lane == 63) wtot[wv] = sc;
  __syncthreads();                       // B2
  {
    float base = sc - c3;
#pragma unroll
    for (int i = 0; i < 3; i++) if (i < wv) base += wtot[i];
    dlp[((tok0 >> 4) * 17) + (tok0 & 15)]             = base + c0;
    dlp[(((tok0 + 1) >> 4) * 17) + ((tok0 + 1) & 15)] = base + c1;
    dlp[(((tok0 + 2) >> 4) * 17) + ((tok0 + 2) & 15)] = base + c2;
    dlp[(((tok0 + 3) >> 4) * 17) + ((tok0 + 3) & 15)] = base + c3;
  }
#pragma unroll
  for (int i = 0; i < 4; i++) {
    int tok = tok0 + i;
    int p = ((tok >> 4) * 17) + (tok & 15);
    uvl[p] = uvl[p] * xcp[p];
  }
  __syncthreads();                       // B3

  int pb = lane * 17;
  float y[16];
#pragma unroll
  for (int i = 0; i < 16; i++) y[i] = 0.f;
  float Dprev = (lane == 0) ? 0.f : dlp[pb - 2];

#pragma unroll 1
  for (int r = 0; r < 4; r++) {
    int n = (wv << 2) + r;
    float An = -__expf(alog[d * NST + n]);
    float st = cs[(size_t)(b * DDIM + d) * NST + n];
    const float* pB = projT + (size_t)(64 + n) * BL + colbase + (lane << 4);
    const float* pC = pB + (size_t)16 * BL;
    float Pp = __expf(An * Dprev);
    float sl = 0.f;
    float pcv[16];
#pragma unroll
    for (int c = 0; c < 4; c++) {
      float4 bv = *(const float4*)(pB + c * 4);
      float4 cv = *(const float4*)(pC + c * 4);
      float bvs[4] = {bv.x, bv.y, bv.z, bv.w};
      float cvs[4] = {cv.x, cv.y, cv.z, cv.w};
#pragma unroll
      for (int j = 0; j < 4; j++) {
        int i = c * 4 + j;
        float P = __expf(An * dlp[pb + i]);
        float w = uvl[pb + i] * bvs[j] * __builtin_amdgcn_rcpf(fmaxf(Pp, 1e-10f));
        sl += w;
        y[i] += (sl * Pp + st * P) * cvs[j];
        pcv[i] = Pp * cvs[j];
        Pp = P;
      }
    }
    float s2 = sl;
#pragma unroll
    for (int off = 1; off < 64; off <<= 1) {
      float u = __shfl_up(s2, off);
      if (lane >= off) s2 += u;
    }
    float Soff = s2 - sl;
#pragma unroll
    for (int i = 0; i < 16; i++) y[i] += Soff * pcv[i];
  }
  __syncthreads();                       // B4
  if (wv == 2) {
#pragma unroll
    for (int i = 0; i < 16; i++) uvl[pb + i] = y[i];
  } else if (wv == 3) {
#pragma unroll
    for (int i = 0; i < 16; i++) dlp[pb + i] = y[i];
  }
  __syncthreads();                       // B5
  if (wv == 0) {
#pragma unroll
    for (int i = 0; i < 16; i++) uvl[pb + i] += y[i];
  } else if (wv == 1) {
#pragma unroll
    for (int i = 0; i < 16; i++) dlp[pb + i] += y[i];
  }
  __syncthreads();                       // B6
  // ---- un-gated y (f32) -> own deltaT slice, coalesced float4 ----
  {
    float4 yo;
    int p0 = ((tok0 >> 4) * 17) + (tok0 & 15);
    int p1 = (((tok0 + 1) >> 4) * 17) + ((tok0 + 1) & 15);
    int p2 = (((tok0 + 2) >> 4) * 17) + ((tok0 + 2) & 15);
    int p3 = (((tok0 + 3) >> 4) * 17) + ((tok0 + 3) & 15);
    yo.x = uvl[p0] + dlp[p0] + xcp[p0] * Dp;
    yo.y = uvl[p1] + dlp[p1] + xcp[p1] * Dp;
    yo.z = uvl[p2] + dlp[p2] + xcp[p2] * Dp;
    yo.w = uvl[p3] + dlp[p3] + xcp[p3] * Dp;
    *(float4*)(drow + tok0) = yo;
  }
}

// ---------------- K3b: gate + transpose: yb[tok][d] = bf16(yT[d][tok] * silu(g[tok][d])) ----
__global__ __launch_bounds__(256) void k_gate(const float* __restrict__ yT,
                                              const u16* __restrict__ xgb,
                                              u16* __restrict__ yb) {
  __shared__ float tile[64 * 65];
  int dt = blockIdx.x & 31;         // d-tile (64 d)
  int tt = blockIdx.x >> 5;         // tok-tile (64 tok)
  int gtok0 = tt << 6;
  int b = gtok0 >> 10, l0 = gtok0 & 1023;
  int d0 = dt << 6;
  int t = threadIdx.x;
  // load yT tile [64 d][64 tok], coalesced rows
#pragma unroll
  for (int i = 0; i < 16; i++) {
    int idx = t + i * 256;
    int r = idx >> 6, c = idx & 63;
    tile[r * 65 + c] = yT[(size_t)(d0 + r) * BL + gtok0 + c];
  }
  __syncthreads();
  // write token-major with gate: rows = tokens, coalesced gate read + yb write
#pragma unroll
  for (int i = 0; i < 16; i++) {
    int idx = t + i * 256;
    int tr = idx >> 6, dc = idx & 63;
    float g = bf2f(xgb[(size_t)(b * XR + 3 + l0 + tr) * 4096 + 2048 + d0 + dc]);
    float yv = tile[dc * 65 + tr];
    yb[(size_t)(gtok0 + tr) * DDIM + d0 + dc] = f2bf(yv * silu_f(g));
  }
}

extern "C" void kernel_launch(void* const* d_in, const int* in_sizes, int n_in,
                              void* d_out, int out_size, void* d_ws, size_t ws_size,
                              hipStream_t stream) {
  const float* inp    = (const float*)d_in[0];
  const float* cstate = (const float*)d_in[1];
  const float* norm_w = (const float*)d_in[2];
  const float* w1     = (const float*)d_in[3];
  const float* b1     = (const float*)d_in[4];
  const float* convw  = (const float*)d_in[5];
  const float* convb  = (const float*)d_in[6];
  const float* xpw    = (const float*)d_in[7];
  const float* xpb    = (const float*)d_in[8];
  const float* dtw    = (const float*)d_in[9];
  const float* dtb    = (const float*)d_in[10];
  const float* alog   = (const float*)d_in[11];
  const float* dparam = (const float*)d_in[12];
  const float* wo     = (const float*)d_in[13];
  const float* bo     = (const float*)d_in[14];
  float* out = (float*)d_out;

  // workspace layout (ws >= 56,156,160 B confirmed R6/R8/R10/R12/R13)
  char* wsb = (char*)d_ws;
  u16*   w1b    = (u16*)(wsb + 0);            //  8,388,608 B  [4096][1024] bf16 (dead after gemm1b)
  u16*   xTbuf  = w1b;                        //  8,388,608 B  xT [2048 d][2048 tok] bf16 (after gemm1b)
  u16*   wob    = (u16*)(wsb + 8388608);      //  4,194,304 B  [1024][2048] bf16
  u16*   whb    = (u16*)(wsb + 12591104);     //    393,216 B  xpw hi bf16 [96][2048]
  u16*   wlb    = (u16*)(wsb + 12984320);     //    393,216 B  xpw lo bf16 [96][2048]
  float* projT  = (float*)(wsb + 13377536);   //    786,432 B  [96][2048] f32
  u16*   xgb    = (u16*)(wsb + 14163968);     // 16,826,368 B  [2][1027][4096] bf16
  u16*   yb     = (u16*)(wsb + 30990336);     //  8,388,608 B  [2][1024][2048] bf16
  u16*   xnb    = yb;                         //  aliases yb (consumed before k_gate writes)
  float* deltaT = (float*)(wsb + 39378944);   // 16,777,216 B  [2048 d][2048 tok] f32
  float* pscr   = deltaT;                     //  first 11.8 MB: xproj K-partials (pre-k_delta)
  float* psplit = deltaT;                     //  16 MB: gemm2 split-K partials (post-k_gate)

  k_prep<<<8408, 256, 0, stream>>>(w1, w1b, wo, wob, xpw, whb, wlb, xgb,
                                   inp, norm_w, xnb);
  k_gemm1b<<<dim3(32, 16), 256, 0, stream>>>(xnb, w1b, b1, xgb);
  k_xT<<<1024, 256, 0, stream>>>(xgb, xTbuf);
  k_xprojT<<<512, 256, 0, stream>>>(xgb, whb, wlb, convw, convb, projT, pscr);
  k_xcomb<<<192, 256, 0, stream>>>(projT, pscr, xpb);
  k_delta<<<1024, 256, 0, stream>>>(projT, dtw, dtb, deltaT);
  k_scan2<<<2 * DDIM, 256, 0, stream>>>(projT, deltaT, xTbuf, convw, convb,
                                        alog, dparam, cstate);
  k_gate<<<1024, 256, 0, stream>>>(deltaT, xgb, yb);
  k_gemm2b<<<dim3(16, 16, 2), 256, 0, stream>>>(yb, wob, psplit);
  k_ocomb<<<2048, 256, 0, stream>>>(psplit, bo, inp, out);
}

// Round 15
// 259.408 us; speedup vs baseline: 1.0239x; 1.0239x over previous
//
#include <hip/hip_runtime.h>
#include <stdint.h>

#define LSEQ 1024
#define HDIM 1024
#define DDIM 2048
#define BL 2048
#define NST 16
#define XR 1027          // 3 halo rows (zeroed in k_prep) + 1024 tokens

typedef unsigned short u16;
typedef __attribute__((ext_vector_type(8))) short bf16x8;
typedef __attribute__((ext_vector_type(4))) float f32x4;

// silu via v_rcp (1-ulp rcp; output tolerance is bf16-dominated)
static __device__ __forceinline__ float silu_f(float v) {
  return v * __builtin_amdgcn_rcpf(1.f + __expf(-v));
}
static __device__ __forceinline__ float bf2f(u16 u) {
  union { float f; unsigned int i; } c; c.i = ((unsigned int)u) << 16; return c.f;
}
static __device__ __forceinline__ u16 f2bf(float f) {
  union { float f; unsigned int i; } c; c.f = f;
  unsigned int r = c.i + 0x7fffu + ((c.i >> 16) & 1u);
  return (u16)(r >> 16);
}
static __device__ __forceinline__ float softplus_f(float v) {
  return (v > 20.f) ? v : __logf(1.f + __expf(v));
}

// ---------------- fused prep: castw(w1), castw(wo), castsplit(xpw), zerohalo, rmsnorm ----
__global__ __launch_bounds__(256) void k_prep(const float* __restrict__ w1,
                                              u16* __restrict__ w1b,
                                              const float* __restrict__ wo,
                                              u16* __restrict__ wob,
                                              const float* __restrict__ xpw,
                                              u16* __restrict__ whb,
                                              u16* __restrict__ wlb,
                                              u16* __restrict__ xgb,
                                              const float* __restrict__ inp,
                                              const float* __restrict__ nw,
                                              u16* __restrict__ xnb) {
  int bidx = blockIdx.x;
  int t = threadIdx.x;
  if (bidx < 4096) {
    int idx = bidx * 256 + t;
    float4 v = ((const float4*)w1)[idx];
    ushort4 o;
    o.x = f2bf(v.x); o.y = f2bf(v.y); o.z = f2bf(v.z); o.w = f2bf(v.w);
    ((ushort4*)w1b)[idx] = o;
  } else if (bidx < 6144) {
    int idx = (bidx - 4096) * 256 + t;
    float4 v = ((const float4*)wo)[idx];
    ushort4 o;
    o.x = f2bf(v.x); o.y = f2bf(v.y); o.z = f2bf(v.z); o.w = f2bf(v.w);
    ((ushort4*)wob)[idx] = o;
  } else if (bidx < 6336) {
    int idx = (bidx - 6144) * 256 + t;
    float4 v = ((const float4*)xpw)[idx];
    ushort4 h, l;
    h.x = f2bf(v.x); l.x = f2bf(v.x - bf2f(h.x));
    h.y = f2bf(v.y); l.y = f2bf(v.y - bf2f(h.y));
    h.z = f2bf(v.z); l.z = f2bf(v.z - bf2f(h.z));
    h.w = f2bf(v.w); l.w = f2bf(v.w - bf2f(h.w));
    ((ushort4*)whb)[idx] = h;
    ((ushort4*)wlb)[idx] = l;
  } else if (bidx < 6360) {
    int idx = (bidx - 6336) * 256 + t;      // 6144 ushort4: 2 b x 3 rows x 1024
    int b = idx / 3072;
    int r = idx - b * 3072;
    ushort4 z4 = {0, 0, 0, 0};
    ((ushort4*)(xgb + (size_t)b * XR * 4096))[r] = z4;
  } else {
    // rmsnorm + normalize -> xnb bf16 [2048][1024]
    int row = bidx - 6360;
    float4 xv = *(const float4*)(inp + (size_t)row * HDIM + t * 4);
    float ss = xv.x * xv.x + xv.y * xv.y + xv.z * xv.z + xv.w * xv.w;
    for (int off = 32; off > 0; off >>= 1) ss += __shfl_down(ss, off);
    __shared__ float red[4];
    if ((t & 63) == 0) red[t >> 6] = ss;
    __syncthreads();
    float tot = red[0] + red[1] + red[2] + red[3];
    float scale = rsqrtf(tot * (1.f / HDIM) + 1e-6f);
    float4 nv = *(const float4*)(nw + t * 4);
    ushort4 o;
    o.x = f2bf(xv.x * scale * nv.x); o.y = f2bf(xv.y * scale * nv.y);
    o.z = f2bf(xv.z * scale * nv.z); o.w = f2bf(xv.w * scale * nv.w);
    ((ushort4*)xnb)[row * 256 + t] = o;
  }
}

// ---------------- K1: in_proj GEMM, 128x128 tile, global_load_lds staging ----------------
// Linear [128][32] LDS tiles (64B rows).  Wave w stages rows w*32..w*32+31 of
// each tile: lds dest = wave-uniform base + lane*16B (HW rule), global source
// per-lane.  Fragment values bitwise identical to the padded-reg-staged path.
__global__ __launch_bounds__(256) void k_gemm1b(const u16* __restrict__ A,
                                                const u16* __restrict__ W,
                                                const float* __restrict__ bias,
                                                u16* __restrict__ xgb) {
  __shared__ u16 Asm[128 * 32];
  __shared__ u16 Wsm[128 * 32];
  int t = threadIdx.x;
  int m0 = blockIdx.y * 128, n0 = blockIdx.x * 128;
  int w = t >> 6, lane = t & 63;
  int wr = w >> 1, wc = w & 1;
  int quad = lane >> 4, mr = lane & 15;
  int srow = (w << 5) + (lane >> 2);       // staging row for load 0 (load 1: +16)
  int scol = (lane & 3) * 8;               // u16 offset within 32-u16 row
  const u16* Ag0 = A + (size_t)(m0 + srow) * HDIM + scol;
  const u16* Ag1 = Ag0 + (size_t)16 * HDIM;
  const u16* Wg0 = W + (size_t)(n0 + srow) * HDIM + scol;
  const u16* Wg1 = Wg0 + (size_t)16 * HDIM;
  u16* ldsA0 = &Asm[(w << 5) * 32];
  u16* ldsA1 = &Asm[((w << 5) + 16) * 32];
  u16* ldsW0 = &Wsm[(w << 5) * 32];
  u16* ldsW1 = &Wsm[((w << 5) + 16) * 32];
  f32x4 z = {0.f, 0.f, 0.f, 0.f};
  f32x4 acc[4][4] = {{z, z, z, z}, {z, z, z, z}, {z, z, z, z}, {z, z, z, z}};
  const u16* arp = &Asm[(wr * 64 + mr) * 32 + quad * 8];
  const u16* brp = &Wsm[(wc * 64 + mr) * 32 + quad * 8];
  for (int k0 = 0; k0 < HDIM; k0 += 32) {
    __syncthreads();                       // prev-iter fragment reads complete
    __builtin_amdgcn_global_load_lds(Ag0 + k0, ldsA0, 16, 0, 0);
    __builtin_amdgcn_global_load_lds(Ag1 + k0, ldsA1, 16, 0, 0);
    __builtin_amdgcn_global_load_lds(Wg0 + k0, ldsW0, 16, 0, 0);
    __builtin_amdgcn_global_load_lds(Wg1 + k0, ldsW1, 16, 0, 0);
    __syncthreads();                       // loads landed (compiler drains vmcnt)
    bf16x8 af[4], bf[4];
#pragma unroll
    for (int i = 0; i < 4; i++) {
      af[i] = *(const bf16x8*)(arp + i * 16 * 32);
      bf[i] = *(const bf16x8*)(brp + i * 16 * 32);
    }
#pragma unroll
    for (int mi = 0; mi < 4; mi++)
#pragma unroll
      for (int ni = 0; ni < 4; ni++)
        acc[mi][ni] = __builtin_amdgcn_mfma_f32_16x16x32_bf16(af[mi], bf[ni],
                                                              acc[mi][ni], 0, 0, 0);
  }
#pragma unroll
  for (int ni = 0; ni < 4; ni++) {
    int col = n0 + wc * 64 + ni * 16 + mr;
    float bv = bias[col];
#pragma unroll
    for (int mi = 0; mi < 4; mi++) {
#pragma unroll
      for (int rr2 = 0; rr2 < 4; rr2++) {
        int rr = m0 + wr * 64 + mi * 16 + quad * 4 + rr2;
        int row = (rr >> 10) * XR + 3 + (rr & 1023);
        xgb[(size_t)row * 4096 + col] = f2bf(acc[mi][ni][rr2] + bv);
      }
    }
  }
}

// ---------------- K1b: transpose x-half of xgb -> xT[2048 d][2048 tok] (bf16) ----------------
__global__ __launch_bounds__(256) void k_xT(const u16* __restrict__ xgb,
                                            u16* __restrict__ xT) {
  __shared__ u16 tile[64][66];      // row stride 66 u16 = 33 dwords (odd -> conflict-free cols)
  int dt = blockIdx.x & 31;         // d-tile (64 d)
  int tt = blockIdx.x >> 5;         // tok-tile (64 tok)
  int gtok0 = tt << 6;
  int b = gtok0 >> 10, l0 = gtok0 & 1023;
  int d0 = dt << 6;
  int t = threadIdx.x;
  const u16* src = xgb + (size_t)(b * XR + 3 + l0) * 4096 + d0;
#pragma unroll
  for (int i = 0; i < 8; i++) {
    int idx = t + i * 256;          // 0..2047
    int row = idx >> 5, uc = idx & 31;
    unsigned int v = *(const unsigned int*)(src + (size_t)row * 4096 + uc * 2);
    tile[row][uc * 2]     = (u16)(v & 0xffffu);
    tile[row][uc * 2 + 1] = (u16)(v >> 16);
  }
  __syncthreads();
#pragma unroll
  for (int i = 0; i < 8; i++) {
    int idx = t + i * 256;
    int r = idx >> 5, c2 = idx & 31;          // d-row r, token pair c2
    unsigned int lo = tile[c2 * 2][r];
    unsigned int hi = tile[c2 * 2 + 1][r];
    *(unsigned int*)(xT + (size_t)(d0 + r) * 2048 + gtok0 + c2 * 2) = lo | (hi << 16);
  }
}

// ---------------- K4: out_proj GEMM, 128x64 tile, split-K x2 -> f32 partials ----------------
__global__ __launch_bounds__(256) void k_gemm2b(const u16* __restrict__ A,
                                                const u16* __restrict__ W,
                                                float* __restrict__ psplit) {
  __shared__ u16 Asm[128 * 40];
  __shared__ u16 Wsm[64 * 40];
  int t = threadIdx.x;
  int m0 = blockIdx.y * 128, n0 = blockIdx.x * 64;
  int kstart = blockIdx.z << 10;
  float* outp = psplit + (size_t)blockIdx.z * 2048 * 1024;
  int srow = t >> 1, koff = (t & 1) * 16;
  const u16* Ag = A + (size_t)(m0 + srow) * DDIM + kstart + koff;
  const u16* Wg = W + (size_t)(n0 + (srow & 63)) * DDIM + kstart + koff;
  int w = t >> 6, lane = t & 63;
  int wr = w >> 1, wc = w & 1;
  int quad = lane >> 4, mr = lane & 15;
  f32x4 z = {0.f, 0.f, 0.f, 0.f};
  f32x4 acc[4][2] = {{z, z}, {z, z}, {z, z}, {z, z}};
  const u16* arp = &Asm[(wr * 64 + mr) * 40 + quad * 8];
  const u16* brp = &Wsm[(wc * 32 + mr) * 40 + quad * 8];
  for (int k0 = 0; k0 < 1024; k0 += 32) {
    uint4 a0 = *(const uint4*)(Ag + k0);
    uint4 a1 = *(const uint4*)(Ag + k0 + 8);
    uint4 w0, w1;
    if (t < 128) {
      w0 = *(const uint4*)(Wg + k0);
      w1 = *(const uint4*)(Wg + k0 + 8);
    }
    __syncthreads();
    *(uint4*)(&Asm[srow * 40 + koff]) = a0;
    *(uint4*)(&Asm[srow * 40 + koff + 8]) = a1;
    if (t < 128) {
      *(uint4*)(&Wsm[srow * 40 + koff]) = w0;
      *(uint4*)(&Wsm[srow * 40 + koff + 8]) = w1;
    }
    __syncthreads();
    bf16x8 af[4], bf[2];
#pragma unroll
    for (int i = 0; i < 4; i++) af[i] = *(const bf16x8*)(arp + i * 16 * 40);
#pragma unroll
    for (int i = 0; i < 2; i++) bf[i] = *(const bf16x8*)(brp + i * 16 * 40);
#pragma unroll
    for (int mi = 0; mi < 4; mi++)
#pragma unroll
      for (int ni = 0; ni < 2; ni++)
        acc[mi][ni] = __builtin_amdgcn_mfma_f32_16x16x32_bf16(af[mi], bf[ni],
                                                              acc[mi][ni], 0, 0, 0);
  }
#pragma unroll
  for (int ni = 0; ni < 2; ni++) {
    int col = n0 + wc * 32 + ni * 16 + mr;
#pragma unroll
    for (int mi = 0; mi < 4; mi++) {
#pragma unroll
      for (int rr2 = 0; rr2 < 4; rr2++) {
        int row = m0 + wr * 64 + mi * 16 + quad * 4 + rr2;
        outp[(size_t)row * 1024 + col] = acc[mi][ni][rr2];
      }
    }
  }
}

// ---------------- K4b: combine split-K partials + bias + residual -> out ----------------
__global__ __launch_bounds__(256) void k_ocomb(const float* __restrict__ psplit,
                                               const float* __restrict__ bias,
                                               const float* __restrict__ resid,
                                               float* __restrict__ out) {
  int idx = blockIdx.x * 256 + threadIdx.x;   // float4 over [2048][1024]
  int colf = idx & 255;
  float4 a = ((const float4*)psplit)[idx];
  float4 b2 = ((const float4*)(psplit + 2048 * 1024))[idx];
  float4 rv = ((const float4*)resid)[idx];
  float4 bv = *(const float4*)(bias + colf * 4);
  float4 o;
  o.x = a.x + b2.x + bv.x + rv.x;
  o.y = a.y + b2.y + bv.y + rv.y;
  o.z = a.z + b2.z + bv.z + rv.z;
  o.w = a.w + b2.w + bv.w + rv.w;
  ((float4*)out)[idx] = o;
}

// ---------------- K2 v3: fused conv+silu + x_proj GEMM -> projT, 16 K-partitions ----
__global__ __launch_bounds__(256) void k_xprojT(const u16* __restrict__ xgb,
                                                const u16* __restrict__ whb,
                                                const u16* __restrict__ wlb,
                                                const float* __restrict__ cw,
                                                const float* __restrict__ cb,
                                                float* __restrict__ projT,
                                                float* __restrict__ pscr) {
  __shared__ u16 Xst[67 * 40];
  __shared__ u16 XH[64 * 40];
  __shared__ u16 XL[64 * 40];
  __shared__ u16 WH[96 * 40];
  __shared__ u16 WL[96 * 40];
  int t = threadIdx.x;
  int tt = blockIdx.x & 31, ks = blockIdx.x >> 5;
  int tokbase = tt << 6;
  int b = tokbase >> 10, l0 = tokbase & 1023;
  int kbase = ks << 7;
  const u16* xbase = xgb + (size_t)(b * XR + l0) * 4096;
  float* outp = (ks == 0) ? projT : (pscr + (size_t)(ks - 1) * 196608);
  int dlane = t & 31, tokg = t >> 5;
  int wvq = t >> 6, lane = t & 63;
  int quad = lane >> 4, mr = lane & 15;
  f32x4 z = {0.f, 0.f, 0.f, 0.f};
  f32x4 acc[6] = {z, z, z, z, z, z};

  for (int it = 0; it < 4; it++) {
    int kc = kbase + (it << 5);
    for (int idx = t; idx < 268; idx += 256) {
      int r = idx >> 2, p = idx & 3;
      uint4 v = *(const uint4*)(xbase + (size_t)r * 4096 + kc + p * 8);
      *(uint4*)(&Xst[r * 40 + p * 8]) = v;
    }
    for (int idx = t; idx < 384; idx += 256) {
      int r = idx >> 2, p = idx & 3;
      *(uint4*)(&WH[r * 40 + p * 8]) = *(const uint4*)(whb + (size_t)r * 2048 + kc + p * 8);
      *(uint4*)(&WL[r * 40 + p * 8]) = *(const uint4*)(wlb + (size_t)r * 2048 + kc + p * 8);
    }
    __syncthreads();
    {
      int d = kc + dlane;
      float4 cwv = *(const float4*)(cw + d * 4);
      float cbv = cb[d];
      float xr[11];
#pragma unroll
      for (int j = 0; j < 11; j++) xr[j] = bf2f(Xst[(tokg * 8 + j) * 40 + dlane]);
#pragma unroll
      for (int jj = 0; jj < 8; jj++) {
        float xc = silu_f(cbv + cwv.x * xr[jj] + cwv.y * xr[jj + 1] +
                          cwv.z * xr[jj + 2] + cwv.w * xr[jj + 3]);
        u16 h = f2bf(xc);
        u16 l = f2bf(xc - bf2f(h));
        XH[(tokg * 8 + jj) * 40 + dlane] = h;
        XL[(tokg * 8 + jj) * 40 + dlane] = l;
      }
    }
    __syncthreads();
    bf16x8 xh = *(const bf16x8*)(&XH[(wvq * 16 + mr) * 40 + quad * 8]);
    bf16x8 xl = *(const bf16x8*)(&XL[(wvq * 16 + mr) * 40 + quad * 8]);
#pragma unroll
    for (int mi = 0; mi < 6; mi++) {
      bf16x8 wh = *(const bf16x8*)(&WH[(mi * 16 + mr) * 40 + quad * 8]);
      bf16x8 wl = *(const bf16x8*)(&WL[(mi * 16 + mr) * 40 + quad * 8]);
      acc[mi] = __builtin_amdgcn_mfma_f32_16x16x32_bf16(wh, xh, acc[mi], 0, 0, 0);
      acc[mi] = __builtin_amdgcn_mfma_f32_16x16x32_bf16(wh, xl, acc[mi], 0, 0, 0);
      acc[mi] = __builtin_amdgcn_mfma_f32_16x16x32_bf16(wl, xh, acc[mi], 0, 0, 0);
    }
    __syncthreads();
  }
#pragma unroll
  for (int mi = 0; mi < 6; mi++) {
#pragma unroll
    for (int rr = 0; rr < 4; rr++) {
      int o = mi * 16 + quad * 4 + rr;
      outp[(size_t)o * BL + tokbase + wvq * 16 + mr] = acc[mi][rr];
    }
  }
}

// ---------------- K2d: combine 16 K-partials + bias into projT ----------------
__global__ __launch_bounds__(256) void k_xcomb(float* __restrict__ projT,
                                               const float* __restrict__ scr,
                                               const float* __restrict__ xpb) {
  int idx = blockIdx.x * 256 + threadIdx.x;
  int o = idx >> 9;
  float4 a = ((const float4*)projT)[idx];
  float bv = xpb[o];
  float sx = bv, sy = bv, sz = bv, sw = bv;
#pragma unroll
  for (int p = 0; p < 15; p++) {
    float4 s = ((const float4*)(scr + (size_t)p * 196608))[idx];
    sx += s.x; sy += s.y; sz += s.z; sw += s.w;
  }
  a.x += sx; a.y += sy; a.z += sz; a.w += sw;
  ((float4*)projT)[idx] = a;
}

// ---------------- K2c: delta GEMM: deltaT[2048 d][2048 tok] = softplus(dtw.projT + dtb) ----
__global__ __launch_bounds__(256) void k_delta(const float* __restrict__ projT,
                                               const float* __restrict__ dtw,
                                               const float* __restrict__ dtb,
                                               float* __restrict__ deltaT) {
  __shared__ float dw_s[16][64];
  int t = threadIdx.x;
  int d0 = (blockIdx.x >> 3) * 16;
  int tokbase = (blockIdx.x & 7) * 256;
  {
    const float* src = dtw + (size_t)d0 * 64;
#pragma unroll
    for (int i = 0; i < 4; i++) {
      int idx = t + i * 256;
      dw_s[idx >> 6][idx & 63] = src[idx];
    }
  }
  __syncthreads();
  int tq = t & 63, dq = t >> 6;
  const float* pr = projT + tokbase + tq * 4;
  int dbase = d0 + dq * 4;
  float acc[4][4];
#pragma unroll
  for (int di = 0; di < 4; di++) {
    float bv = dtb[dbase + di];
    acc[di][0] = bv; acc[di][1] = bv; acc[di][2] = bv; acc[di][3] = bv;
  }
#pragma unroll 8
  for (int r = 0; r < 64; r++) {
    float4 pv = *(const float4*)(pr + (size_t)r * BL);
#pragma unroll
    for (int di = 0; di < 4; di++) {
      float wk = dw_s[dq * 4 + di][r];
      acc[di][0] += pv.x * wk; acc[di][1] += pv.y * wk;
      acc[di][2] += pv.z * wk; acc[di][3] += pv.w * wk;
    }
  }
#pragma unroll
  for (int di = 0; di < 4; di++) {
    float4 o;
    o.x = softplus_f(acc[di][0]); o.y = softplus_f(acc[di][1]);
    o.z = softplus_f(acc[di][2]); o.w = softplus_f(acc[di][3]);
    *(float4*)(deltaT + (size_t)(dbase + di) * BL + tokbase + tq * 4) = o;
  }
}

// ---------------- K3 (R13 version): selective scan, fully coalesced ----------------
// Reverted from R14's pcv variant (regressed 57->64us: compiler restructured to
// 52 VGPR with worse schedule).  Phase 2 recomputes Pp (bitwise-identical input)
// and reloads Cv from L2; un-gated f32 y written into own deltaT slice.
__global__ __launch_bounds__(256) void k_scan2(const float* __restrict__ projT,
                                               float* __restrict__ deltaT,
                                               const u16* __restrict__ xT,
                                               const float* __restrict__ cw,
                                               const float* __restrict__ cb,
                                               const float* __restrict__ alog,
                                               const float* __restrict__ dparam,
                                               const float* __restrict__ cs) {
  __shared__ float wtot[4];
  __shared__ float xcp[1088];
  __shared__ float uvl[1088];
  __shared__ float dlp[1088];

  int t = threadIdx.x;
  int cidx = ((blockIdx.x & 7) << 9) | (blockIdx.x >> 3);   // (b,d)
  int b = cidx >> 11;
  int d = cidx & (DDIM - 1);
  int wv = t >> 6, lane = t & 63;

  float4 cwv = *(const float4*)(cw + d * 4);
  float cbv = cb[d];
  float Dp = dparam[d];
  int colbase = b << 10;
  int tok0 = t << 2;
  float* drow = deltaT + (size_t)d * BL + colbase;

  float4 dv = *(const float4*)(drow + tok0);

  // ---- stage x row (coalesced from xT) into dlp-aliased xls ----
  float* xls = dlp;
  if (t < 3) xls[t] = 0.f;
  {
    ushort4 xv = ((const ushort4*)(xT + (size_t)d * 2048 + colbase))[t];
    xls[3 + tok0 + 0] = bf2f(xv.x);
    xls[3 + tok0 + 1] = bf2f(xv.y);
    xls[3 + tok0 + 2] = bf2f(xv.z);
    xls[3 + tok0 + 3] = bf2f(xv.w);
  }
  __syncthreads();                       // B1

#pragma unroll
  for (int i = 0; i < 4; i++) {
    int tok = tok0 + i;
    float xc = silu_f(cbv + cwv.x * xls[tok] + cwv.y * xls[tok + 1] +
                      cwv.z * xls[tok + 2] + cwv.w * xls[tok + 3]);
    xcp[((tok >> 4) * 17) + (tok & 15)] = xc;
  }
  float d0 = dv.x, d1 = dv.y, d2 = dv.z, d3 = dv.w;
  uvl[((tok0 >> 4) * 17) + (tok0 & 15)]             = d0;
  uvl[(((tok0 + 1) >> 4) * 17) + ((tok0 + 1) & 15)] = d1;
  uvl[(((tok0 + 2) >> 4) * 17) + ((tok0 + 2) & 15)] = d2;
  uvl[(((tok0 + 3) >> 4) * 17) + ((tok0 + 3) & 15)] = d3;
  float c0 = d0, c1 = c0 + d1, c2 = c1 + d2, c3 = c2 + d3;
  float sc = c3;
#pragma unroll
  for (int off = 1; off < 64; off <<= 1) {
    float u = __shfl_up(sc, off);
    if (lane >= off) sc += u;
  }
  if (lane == 63) wtot[wv] = sc;
  __syncthreads();                       // B2
  {
    float base = sc - c3;
#pragma unroll
    for (int i = 0; i < 3; i++) if (i < wv) base += wtot[i];
    dlp[((tok0 >> 4) * 17) + (tok0 & 15)]             = base + c0;
    dlp[(((tok0 + 1) >> 4) * 17) + ((tok0 + 1) & 15)] = base + c1;
    dlp[(((tok0 + 2) >> 4) * 17) + ((tok0 + 2) & 15)] = base + c2;
    dlp[(((tok0 + 3) >> 4) * 17) + ((tok0 + 3) & 15)] = base + c3;
  }
#pragma unroll
  for (int i = 0; i < 4; i++) {
    int tok = tok0 + i;
    int p = ((tok >> 4) * 17) + (tok & 15);
    uvl[p] = uvl[p] * xcp[p];
  }
  __syncthreads();                       // B3

  int pb = lane * 17;
  float y[16];
#pragma unroll
  for (int i = 0; i < 16; i++) y[i] = 0.f;
  float Dprev = (lane == 0) ? 0.f : dlp[pb - 2];

#pragma unroll 1
  for (int r = 0; r < 4; r++) {
    int n = (wv << 2) + r;
    float An = -__expf(alog[d * NST + n]);
    float st = cs[(size_t)(b * DDIM + d) * NST + n];
    const float* pB = projT + (size_t)(64 + n) * BL + colbase + (lane << 4);
    const float* pC = pB + (size_t)16 * BL;
    float Pp = __expf(An * Dprev);
    float sl = 0.f;
#pragma unroll
    for (int c = 0; c < 4; c++) {
      float4 bv = *(const float4*)(pB + c * 4);
      float4 cv = *(const float4*)(pC + c * 4);
      float bvs[4] = {bv.x, bv.y, bv.z, bv.w};
      float cvs[4] = {cv.x, cv.y, cv.z, cv.w};
#pragma unroll
      for (int j = 0; j < 4; j++) {
        int i = c * 4 + j;
        float P = __expf(An * dlp[pb + i]);
        float w = uvl[pb + i] * bvs[j] * __builtin_amdgcn_rcpf(fmaxf(Pp, 1e-10f));
        sl += w;
        y[i] += (sl * Pp + st * P) * cvs[j];
        Pp = P;
      }
    }
    float s2 = sl;
#pragma unroll
    for (int off = 1; off < 64; off <<= 1) {
      float u = __shfl_up(s2, off);
      if (lane >= off) s2 += u;
    }
    float Soff = s2 - sl;
#pragma unroll
    for (int c = 0; c < 4; c++) {
      float4 cv = *(const float4*)(pC + c * 4);
      float cvs[4] = {cv.x, cv.y, cv.z, cv.w};
#pragma unroll
      for (int j = 0; j < 4; j++) {
        int i = c * 4 + j;
        float dlm = (i == 0) ? Dprev : dlp[pb + i - 1];
        y[i] += Soff * __expf(An * dlm) * cvs[j];
      }
    }
  }
  __syncthreads();                       // B4
  if (wv == 2) {
#pragma unroll
    for (int i = 0; i < 16; i++) uvl[pb + i] = y[i];
  } else if (wv == 3) {
#pragma unroll
    for (int i = 0; i < 16; i++) dlp[pb + i] = y[i];
  }
  __syncthreads();                       // B5
  if (wv == 0) {
#pragma unroll
    for (int i = 0; i < 16; i++) uvl[pb + i] += y[i];
  } else if (wv == 1) {
#pragma unroll
    for (int i = 0; i < 16; i++) dlp[pb + i] += y[i];
  }
  __syncthreads();                       // B6
  // ---- un-gated y (f32) -> own deltaT slice, coalesced float4 ----
  {
    float4 yo;
    int p0 = ((tok0 >> 4) * 17) + (tok0 & 15);
    int p1 = (((tok0 + 1) >> 4) * 17) + ((tok0 + 1) & 15);
    int p2 = (((tok0 + 2) >> 4) * 17) + ((tok0 + 2) & 15);
    int p3 = (((tok0 + 3) >> 4) * 17) + ((tok0 + 3) & 15);
    yo.x = uvl[p0] + dlp[p0] + xcp[p0] * Dp;
    yo.y = uvl[p1] + dlp[p1] + xcp[p1] * Dp;
    yo.z = uvl[p2] + dlp[p2] + xcp[p2] * Dp;
    yo.w = uvl[p3] + dlp[p3] + xcp[p3] * Dp;
    *(float4*)(drow + tok0) = yo;
  }
}

// ---------------- K3b: gate + transpose: yb[tok][d] = bf16(yT[d][tok] * silu(g[tok][d])) ----
__global__ __launch_bounds__(256) void k_gate(const float* __restrict__ yT,
                                              const u16* __restrict__ xgb,
                                              u16* __restrict__ yb) {
  __shared__ float tile[64 * 65];
  int dt = blockIdx.x & 31;         // d-tile (64 d)
  int tt = blockIdx.x >> 5;         // tok-tile (64 tok)
  int gtok0 = tt << 6;
  int b = gtok0 >> 10, l0 = gtok0 & 1023;
  int d0 = dt << 6;
  int t = threadIdx.x;
  // load yT tile [64 d][64 tok], coalesced rows
#pragma unroll
  for (int i = 0; i < 16; i++) {
    int idx = t + i * 256;
    int r = idx >> 6, c = idx & 63;
    tile[r * 65 + c] = yT[(size_t)(d0 + r) * BL + gtok0 + c];
  }
  __syncthreads();
  // write token-major with gate: rows = tokens, coalesced gate read + yb write
#pragma unroll
  for (int i = 0; i < 16; i++) {
    int idx = t + i * 256;
    int tr = idx >> 6, dc = idx & 63;
    float g = bf2f(xgb[(size_t)(b * XR + 3 + l0 + tr) * 4096 + 2048 + d0 + dc]);
    float yv = tile[dc * 65 + tr];
    yb[(size_t)(gtok0 + tr) * DDIM + d0 + dc] = f2bf(yv * silu_f(g));
  }
}

extern "C" void kernel_launch(void* const* d_in, const int* in_sizes, int n_in,
                              void* d_out, int out_size, void* d_ws, size_t ws_size,
                              hipStream_t stream) {
  const float* inp    = (const float*)d_in[0];
  const float* cstate = (const float*)d_in[1];
  const float* norm_w = (const float*)d_in[2];
  const float* w1     = (const float*)d_in[3];
  const float* b1     = (const float*)d_in[4];
  const float* convw  = (const float*)d_in[5];
  const float* convb  = (const float*)d_in[6];
  const float* xpw    = (const float*)d_in[7];
  const float* xpb    = (const float*)d_in[8];
  const float* dtw    = (const float*)d_in[9];
  const float* dtb    = (const float*)d_in[10];
  const float* alog   = (const float*)d_in[11];
  const float* dparam = (const float*)d_in[12];
  const float* wo     = (const float*)d_in[13];
  const float* bo     = (const float*)d_in[14];
  float* out = (float*)d_out;

  // workspace layout (ws >= 56,156,160 B confirmed R6/R8/R10/R12/R13)
  char* wsb = (char*)d_ws;
  u16*   w1b    = (u16*)(wsb + 0);            //  8,388,608 B  [4096][1024] bf16 (dead after gemm1b)
  u16*   xTbuf  = w1b;                        //  8,388,608 B  xT [2048 d][2048 tok] bf16 (after gemm1b)
  u16*   wob    = (u16*)(wsb + 8388608);      //  4,194,304 B  [1024][2048] bf16
  u16*   whb    = (u16*)(wsb + 12591104);     //    393,216 B  xpw hi bf16 [96][2048]
  u16*   wlb    = (u16*)(wsb + 12984320);     //    393,216 B  xpw lo bf16 [96][2048]
  float* projT  = (float*)(wsb + 13377536);   //    786,432 B  [96][2048] f32
  u16*   xgb    = (u16*)(wsb + 14163968);     // 16,826,368 B  [2][1027][4096] bf16
  u16*   yb     = (u16*)(wsb + 30990336);     //  8,388,608 B  [2][1024][2048] bf16
  u16*   xnb    = yb;                         //  aliases yb (consumed before k_gate writes)
  float* deltaT = (float*)(wsb + 39378944);   // 16,777,216 B  [2048 d][2048 tok] f32
  float* pscr   = deltaT;                     //  first 11.8 MB: xproj K-partials (pre-k_delta)
  float* psplit = deltaT;                     //  16 MB: gemm2 split-K partials (post-k_gate)

  k_prep<<<8408, 256, 0, stream>>>(w1, w1b, wo, wob, xpw, whb, wlb, xgb,
                                   inp, norm_w, xnb);
  k_gemm1b<<<dim3(32, 16), 256, 0, stream>>>(xnb, w1b, b1, xgb);
  k_xT<<<1024, 256, 0, stream>>>(xgb, xTbuf);
  k_xprojT<<<512, 256, 0, stream>>>(xgb, whb, wlb, convw, convb, projT, pscr);
  k_xcomb<<<192, 256, 0, stream>>>(projT, pscr, xpb);
  k_delta<<<1024, 256, 0, stream>>>(projT, dtw, dtb, deltaT);
  k_scan2<<<2 * DDIM, 256, 0, stream>>>(projT, deltaT, xTbuf, convw, convb,
                                        alog, dparam, cstate);
  k_gate<<<1024, 256, 0, stream>>>(deltaT, xgb, yb);
  k_gemm2b<<<dim3(16, 16, 2), 256, 0, stream>>>(yb, wob, psplit);
  k_ocomb<<<2048, 256, 0, stream>>>(psplit, bo, inp, out);
}

// Round 16
// 253.791 us; speedup vs baseline: 1.0466x; 1.0221x over previous
//
#include <hip/hip_runtime.h>
#include <stdint.h>

#define LSEQ 1024
#define HDIM 1024
#define DDIM 2048
#define BL 2048
#define NST 16
#define XR 1027          // 3 halo rows (zeroed in k_prep) + 1024 tokens

typedef unsigned short u16;
typedef __attribute__((ext_vector_type(8))) short bf16x8;
typedef __attribute__((ext_vector_type(4))) float f32x4;

// silu via v_rcp (1-ulp rcp; output tolerance is bf16-dominated)
static __device__ __forceinline__ float silu_f(float v) {
  return v * __builtin_amdgcn_rcpf(1.f + __expf(-v));
}
static __device__ __forceinline__ float bf2f(u16 u) {
  union { float f; unsigned int i; } c; c.i = ((unsigned int)u) << 16; return c.f;
}
static __device__ __forceinline__ u16 f2bf(float f) {
  union { float f; unsigned int i; } c; c.f = f;
  unsigned int r = c.i + 0x7fffu + ((c.i >> 16) & 1u);
  return (u16)(r >> 16);
}
static __device__ __forceinline__ float softplus_f(float v) {
  return (v > 20.f) ? v : __logf(1.f + __expf(v));
}

// ---------------- fused prep: castw(w1), castw(wo), castsplit(xpw), zerohalo, rmsnorm ----
__global__ __launch_bounds__(256) void k_prep(const float* __restrict__ w1,
                                              u16* __restrict__ w1b,
                                              const float* __restrict__ wo,
                                              u16* __restrict__ wob,
                                              const float* __restrict__ xpw,
                                              u16* __restrict__ whb,
                                              u16* __restrict__ wlb,
                                              u16* __restrict__ xgb,
                                              const float* __restrict__ inp,
                                              const float* __restrict__ nw,
                                              u16* __restrict__ xnb) {
  int bidx = blockIdx.x;
  int t = threadIdx.x;
  if (bidx < 4096) {
    int idx = bidx * 256 + t;
    float4 v = ((const float4*)w1)[idx];
    ushort4 o;
    o.x = f2bf(v.x); o.y = f2bf(v.y); o.z = f2bf(v.z); o.w = f2bf(v.w);
    ((ushort4*)w1b)[idx] = o;
  } else if (bidx < 6144) {
    int idx = (bidx - 4096) * 256 + t;
    float4 v = ((const float4*)wo)[idx];
    ushort4 o;
    o.x = f2bf(v.x); o.y = f2bf(v.y); o.z = f2bf(v.z); o.w = f2bf(v.w);
    ((ushort4*)wob)[idx] = o;
  } else if (bidx < 6336) {
    int idx = (bidx - 6144) * 256 + t;
    float4 v = ((const float4*)xpw)[idx];
    ushort4 h, l;
    h.x = f2bf(v.x); l.x = f2bf(v.x - bf2f(h.x));
    h.y = f2bf(v.y); l.y = f2bf(v.y - bf2f(h.y));
    h.z = f2bf(v.z); l.z = f2bf(v.z - bf2f(h.z));
    h.w = f2bf(v.w); l.w = f2bf(v.w - bf2f(h.w));
    ((ushort4*)whb)[idx] = h;
    ((ushort4*)wlb)[idx] = l;
  } else if (bidx < 6360) {
    int idx = (bidx - 6336) * 256 + t;      // 6144 ushort4: 2 b x 3 rows x 1024
    int b = idx / 3072;
    int r = idx - b * 3072;
    ushort4 z4 = {0, 0, 0, 0};
    ((ushort4*)(xgb + (size_t)b * XR * 4096))[r] = z4;
  } else {
    // rmsnorm + normalize -> xnb bf16 [2048][1024]
    int row = bidx - 6360;
    float4 xv = *(const float4*)(inp + (size_t)row * HDIM + t * 4);
    float ss = xv.x * xv.x + xv.y * xv.y + xv.z * xv.z + xv.w * xv.w;
    for (int off = 32; off > 0; off >>= 1) ss += __shfl_down(ss, off);
    __shared__ float red[4];
    if ((t & 63) == 0) red[t >> 6] = ss;
    __syncthreads();
    float tot = red[0] + red[1] + red[2] + red[3];
    float scale = rsqrtf(tot * (1.f / HDIM) + 1e-6f);
    float4 nv = *(const float4*)(nw + t * 4);
    ushort4 o;
    o.x = f2bf(xv.x * scale * nv.x); o.y = f2bf(xv.y * scale * nv.y);
    o.z = f2bf(xv.z * scale * nv.z); o.w = f2bf(xv.w * scale * nv.w);
    ((ushort4*)xnb)[row * 256 + t] = o;
  }
}

// ---------------- K1: in_proj GEMM, 128x128 tile, global_load_lds staging ----------------
__global__ __launch_bounds__(256) void k_gemm1b(const u16* __restrict__ A,
                                                const u16* __restrict__ W,
                                                const float* __restrict__ bias,
                                                u16* __restrict__ xgb) {
  __shared__ u16 Asm[128 * 32];
  __shared__ u16 Wsm[128 * 32];
  int t = threadIdx.x;
  int m0 = blockIdx.y * 128, n0 = blockIdx.x * 128;
  int w = t >> 6, lane = t & 63;
  int wr = w >> 1, wc = w & 1;
  int quad = lane >> 4, mr = lane & 15;
  int srow = (w << 5) + (lane >> 2);       // staging row for load 0 (load 1: +16)
  int scol = (lane & 3) * 8;               // u16 offset within 32-u16 row
  const u16* Ag0 = A + (size_t)(m0 + srow) * HDIM + scol;
  const u16* Ag1 = Ag0 + (size_t)16 * HDIM;
  const u16* Wg0 = W + (size_t)(n0 + srow) * HDIM + scol;
  const u16* Wg1 = Wg0 + (size_t)16 * HDIM;
  u16* ldsA0 = &Asm[(w << 5) * 32];
  u16* ldsA1 = &Asm[((w << 5) + 16) * 32];
  u16* ldsW0 = &Wsm[(w << 5) * 32];
  u16* ldsW1 = &Wsm[((w << 5) + 16) * 32];
  f32x4 z = {0.f, 0.f, 0.f, 0.f};
  f32x4 acc[4][4] = {{z, z, z, z}, {z, z, z, z}, {z, z, z, z}, {z, z, z, z}};
  const u16* arp = &Asm[(wr * 64 + mr) * 32 + quad * 8];
  const u16* brp = &Wsm[(wc * 64 + mr) * 32 + quad * 8];
  for (int k0 = 0; k0 < HDIM; k0 += 32) {
    __syncthreads();                       // prev-iter fragment reads complete
    __builtin_amdgcn_global_load_lds(Ag0 + k0, ldsA0, 16, 0, 0);
    __builtin_amdgcn_global_load_lds(Ag1 + k0, ldsA1, 16, 0, 0);
    __builtin_amdgcn_global_load_lds(Wg0 + k0, ldsW0, 16, 0, 0);
    __builtin_amdgcn_global_load_lds(Wg1 + k0, ldsW1, 16, 0, 0);
    __syncthreads();                       // loads landed (compiler drains vmcnt)
    bf16x8 af[4], bf[4];
#pragma unroll
    for (int i = 0; i < 4; i++) {
      af[i] = *(const bf16x8*)(arp + i * 16 * 32);
      bf[i] = *(const bf16x8*)(brp + i * 16 * 32);
    }
#pragma unroll
    for (int mi = 0; mi < 4; mi++)
#pragma unroll
      for (int ni = 0; ni < 4; ni++)
        acc[mi][ni] = __builtin_amdgcn_mfma_f32_16x16x32_bf16(af[mi], bf[ni],
                                                              acc[mi][ni], 0, 0, 0);
  }
#pragma unroll
  for (int ni = 0; ni < 4; ni++) {
    int col = n0 + wc * 64 + ni * 16 + mr;
    float bv = bias[col];
#pragma unroll
    for (int mi = 0; mi < 4; mi++) {
#pragma unroll
      for (int rr2 = 0; rr2 < 4; rr2++) {
        int rr = m0 + wr * 64 + mi * 16 + quad * 4 + rr2;
        int row = (rr >> 10) * XR + 3 + (rr & 1023);
        xgb[(size_t)row * 4096 + col] = f2bf(acc[mi][ni][rr2] + bv);
      }
    }
  }
}

// ---------------- K1b: transpose x-half of xgb -> xT[2048 d][2048 tok] (bf16) ----------------
__global__ __launch_bounds__(256) void k_xT(const u16* __restrict__ xgb,
                                            u16* __restrict__ xT) {
  __shared__ u16 tile[64][66];      // row stride 66 u16 = 33 dwords (odd -> conflict-free cols)
  int dt = blockIdx.x & 31;         // d-tile (64 d)
  int tt = blockIdx.x >> 5;         // tok-tile (64 tok)
  int gtok0 = tt << 6;
  int b = gtok0 >> 10, l0 = gtok0 & 1023;
  int d0 = dt << 6;
  int t = threadIdx.x;
  const u16* src = xgb + (size_t)(b * XR + 3 + l0) * 4096 + d0;
#pragma unroll
  for (int i = 0; i < 8; i++) {
    int idx = t + i * 256;          // 0..2047
    int row = idx >> 5, uc = idx & 31;
    unsigned int v = *(const unsigned int*)(src + (size_t)row * 4096 + uc * 2);
    tile[row][uc * 2]     = (u16)(v & 0xffffu);
    tile[row][uc * 2 + 1] = (u16)(v >> 16);
  }
  __syncthreads();
#pragma unroll
  for (int i = 0; i < 8; i++) {
    int idx = t + i * 256;
    int r = idx >> 5, c2 = idx & 31;          // d-row r, token pair c2
    unsigned int lo = tile[c2 * 2][r];
    unsigned int hi = tile[c2 * 2 + 1][r];
    *(unsigned int*)(xT + (size_t)(d0 + r) * 2048 + gtok0 + c2 * 2) = lo | (hi << 16);
  }
}

// ---------------- K4: out_proj GEMM, 128x64 tile, split-K x2, gll staging ----------------
// Asm 128 rows = 4 waves x 32 rows (2 loads); Wsm 64 rows = 4 waves x 16 rows
// (1 load) -> no divergent guard.  Linear [.][32] tiles; fragments bitwise
// identical to the reg-staged path.
__global__ __launch_bounds__(256) void k_gemm2b(const u16* __restrict__ A,
                                                const u16* __restrict__ W,
                                                float* __restrict__ psplit) {
  __shared__ u16 Asm[128 * 32];
  __shared__ u16 Wsm[64 * 32];
  int t = threadIdx.x;
  int m0 = blockIdx.y * 128, n0 = blockIdx.x * 64;
  int kstart = blockIdx.z << 10;
  float* outp = psplit + (size_t)blockIdx.z * 2048 * 1024;
  int w = t >> 6, lane = t & 63;
  int wr = w >> 1, wc = w & 1;
  int quad = lane >> 4, mr = lane & 15;
  int srowA = (w << 5) + (lane >> 2);      // A staging rows (2 loads: +16)
  int srowW = (w << 4) + (lane >> 2);      // W staging rows (1 load)
  int scol = (lane & 3) * 8;
  const u16* Ag0 = A + (size_t)(m0 + srowA) * DDIM + kstart + scol;
  const u16* Ag1 = Ag0 + (size_t)16 * DDIM;
  const u16* Wg0 = W + (size_t)(n0 + srowW) * DDIM + kstart + scol;
  u16* ldsA0 = &Asm[(w << 5) * 32];
  u16* ldsA1 = &Asm[((w << 5) + 16) * 32];
  u16* ldsW0 = &Wsm[(w << 4) * 32];
  f32x4 z = {0.f, 0.f, 0.f, 0.f};
  f32x4 acc[4][2] = {{z, z}, {z, z}, {z, z}, {z, z}};
  const u16* arp = &Asm[(wr * 64 + mr) * 32 + quad * 8];
  const u16* brp = &Wsm[(wc * 32 + mr) * 32 + quad * 8];
  for (int k0 = 0; k0 < 1024; k0 += 32) {
    __syncthreads();                       // prev-iter fragment reads complete
    __builtin_amdgcn_global_load_lds(Ag0 + k0, ldsA0, 16, 0, 0);
    __builtin_amdgcn_global_load_lds(Ag1 + k0, ldsA1, 16, 0, 0);
    __builtin_amdgcn_global_load_lds(Wg0 + k0, ldsW0, 16, 0, 0);
    __syncthreads();                       // loads landed
    bf16x8 af[4], bf[2];
#pragma unroll
    for (int i = 0; i < 4; i++) af[i] = *(const bf16x8*)(arp + i * 16 * 32);
#pragma unroll
    for (int i = 0; i < 2; i++) bf[i] = *(const bf16x8*)(brp + i * 16 * 32);
#pragma unroll
    for (int mi = 0; mi < 4; mi++)
#pragma unroll
      for (int ni = 0; ni < 2; ni++)
        acc[mi][ni] = __builtin_amdgcn_mfma_f32_16x16x32_bf16(af[mi], bf[ni],
                                                              acc[mi][ni], 0, 0, 0);
  }
#pragma unroll
  for (int ni = 0; ni < 2; ni++) {
    int col = n0 + wc * 32 + ni * 16 + mr;
#pragma unroll
    for (int mi = 0; mi < 4; mi++) {
#pragma unroll
      for (int rr2 = 0; rr2 < 4; rr2++) {
        int row = m0 + wr * 64 + mi * 16 + quad * 4 + rr2;
        outp[(size_t)row * 1024 + col] = acc[mi][ni][rr2];
      }
    }
  }
}

// ---------------- K4b: combine split-K partials + bias + residual -> out ----------------
__global__ __launch_bounds__(256) void k_ocomb(const float* __restrict__ psplit,
                                               const float* __restrict__ bias,
                                               const float* __restrict__ resid,
                                               float* __restrict__ out) {
  int idx = blockIdx.x * 256 + threadIdx.x;   // float4 over [2048][1024]
  int colf = idx & 255;
  float4 a = ((const float4*)psplit)[idx];
  float4 b2 = ((const float4*)(psplit + 2048 * 1024))[idx];
  float4 rv = ((const float4*)resid)[idx];
  float4 bv = *(const float4*)(bias + colf * 4);
  float4 o;
  o.x = a.x + b2.x + bv.x + rv.x;
  o.y = a.y + b2.y + bv.y + rv.y;
  o.z = a.z + b2.z + bv.z + rv.z;
  o.w = a.w + b2.w + bv.w + rv.w;
  ((float4*)out)[idx] = o;
}

// ---------------- K2 v3: fused conv+silu + x_proj GEMM -> projT, 16 K-partitions ----
__global__ __launch_bounds__(256) void k_xprojT(const u16* __restrict__ xgb,
                                                const u16* __restrict__ whb,
                                                const u16* __restrict__ wlb,
                                                const float* __restrict__ cw,
                                                const float* __restrict__ cb,
                                                float* __restrict__ projT,
                                                float* __restrict__ pscr) {
  __shared__ u16 Xst[67 * 40];
  __shared__ u16 XH[64 * 40];
  __shared__ u16 XL[64 * 40];
  __shared__ u16 WH[96 * 40];
  __shared__ u16 WL[96 * 40];
  int t = threadIdx.x;
  int tt = blockIdx.x & 31, ks = blockIdx.x >> 5;
  int tokbase = tt << 6;
  int b = tokbase >> 10, l0 = tokbase & 1023;
  int kbase = ks << 7;
  const u16* xbase = xgb + (size_t)(b * XR + l0) * 4096;
  float* outp = (ks == 0) ? projT : (pscr + (size_t)(ks - 1) * 196608);
  int dlane = t & 31, tokg = t >> 5;
  int wvq = t >> 6, lane = t & 63;
  int quad = lane >> 4, mr = lane & 15;
  f32x4 z = {0.f, 0.f, 0.f, 0.f};
  f32x4 acc[6] = {z, z, z, z, z, z};

  for (int it = 0; it < 4; it++) {
    int kc = kbase + (it << 5);
    for (int idx = t; idx < 268; idx += 256) {
      int r = idx >> 2, p = idx & 3;
      uint4 v = *(const uint4*)(xbase + (size_t)r * 4096 + kc + p * 8);
      *(uint4*)(&Xst[r * 40 + p * 8]) = v;
    }
    for (int idx = t; idx < 384; idx += 256) {
      int r = idx >> 2, p = idx & 3;
      *(uint4*)(&WH[r * 40 + p * 8]) = *(const uint4*)(whb + (size_t)r * 2048 + kc + p * 8);
      *(uint4*)(&WL[r * 40 + p * 8]) = *(const uint4*)(wlb + (size_t)r * 2048 + kc + p * 8);
    }
    __syncthreads();
    {
      int d = kc + dlane;
      float4 cwv = *(const float4*)(cw + d * 4);
      float cbv = cb[d];
      float xr[11];
#pragma unroll
      for (int j = 0; j < 11; j++) xr[j] = bf2f(Xst[(tokg * 8 + j) * 40 + dlane]);
#pragma unroll
      for (int jj = 0; jj < 8; jj++) {
        float xc = silu_f(cbv + cwv.x * xr[jj] + cwv.y * xr[jj + 1] +
                          cwv.z * xr[jj + 2] + cwv.w * xr[jj + 3]);
        u16 h = f2bf(xc);
        u16 l = f2bf(xc - bf2f(h));
        XH[(tokg * 8 + jj) * 40 + dlane] = h;
        XL[(tokg * 8 + jj) * 40 + dlane] = l;
      }
    }
    __syncthreads();
    bf16x8 xh = *(const bf16x8*)(&XH[(wvq * 16 + mr) * 40 + quad * 8]);
    bf16x8 xl = *(const bf16x8*)(&XL[(wvq * 16 + mr) * 40 + quad * 8]);
#pragma unroll
    for (int mi = 0; mi < 6; mi++) {
      bf16x8 wh = *(const bf16x8*)(&WH[(mi * 16 + mr) * 40 + quad * 8]);
      bf16x8 wl = *(const bf16x8*)(&WL[(mi * 16 + mr) * 40 + quad * 8]);
      acc[mi] = __builtin_amdgcn_mfma_f32_16x16x32_bf16(wh, xh, acc[mi], 0, 0, 0);
      acc[mi] = __builtin_amdgcn_mfma_f32_16x16x32_bf16(wh, xl, acc[mi], 0, 0, 0);
      acc[mi] = __builtin_amdgcn_mfma_f32_16x16x32_bf16(wl, xh, acc[mi], 0, 0, 0);
    }
    __syncthreads();
  }
#pragma unroll
  for (int mi = 0; mi < 6; mi++) {
#pragma unroll
    for (int rr = 0; rr < 4; rr++) {
      int o = mi * 16 + quad * 4 + rr;
      outp[(size_t)o * BL + tokbase + wvq * 16 + mr] = acc[mi][rr];
    }
  }
}

// ---------------- K2d: combine 16 K-partials + bias into projT ----------------
__global__ __launch_bounds__(256) void k_xcomb(float* __restrict__ projT,
                                               const float* __restrict__ scr,
                                               const float* __restrict__ xpb) {
  int idx = blockIdx.x * 256 + threadIdx.x;
  int o = idx >> 9;
  float4 a = ((const float4*)projT)[idx];
  float bv = xpb[o];
  float sx = bv, sy = bv, sz = bv, sw = bv;
#pragma unroll
  for (int p = 0; p < 15; p++) {
    float4 s = ((const float4*)(scr + (size_t)p * 196608))[idx];
    sx += s.x; sy += s.y; sz += s.z; sw += s.w;
  }
  a.x += sx; a.y += sy; a.z += sz; a.w += sw;
  ((float4*)projT)[idx] = a;
}

// ---------------- K2c: delta GEMM: deltaT[2048 d][2048 tok] = softplus(dtw.projT + dtb) ----
__global__ __launch_bounds__(256) void k_delta(const float* __restrict__ projT,
                                               const float* __restrict__ dtw,
                                               const float* __restrict__ dtb,
                                               float* __restrict__ deltaT) {
  __shared__ float dw_s[16][64];
  int t = threadIdx.x;
  int d0 = (blockIdx.x >> 3) * 16;
  int tokbase = (blockIdx.x & 7) * 256;
  {
    const float* src = dtw + (size_t)d0 * 64;
#pragma unroll
    for (int i = 0; i < 4; i++) {
      int idx = t + i * 256;
      dw_s[idx >> 6][idx & 63] = src[idx];
    }
  }
  __syncthreads();
  int tq = t & 63, dq = t >> 6;
  const float* pr = projT + tokbase + tq * 4;
  int dbase = d0 + dq * 4;
  float acc[4][4];
#pragma unroll
  for (int di = 0; di < 4; di++) {
    float bv = dtb[dbase + di];
    acc[di][0] = bv; acc[di][1] = bv; acc[di][2] = bv; acc[di][3] = bv;
  }
#pragma unroll 8
  for (int r = 0; r < 64; r++) {
    float4 pv = *(const float4*)(pr + (size_t)r * BL);
#pragma unroll
    for (int di = 0; di < 4; di++) {
      float wk = dw_s[dq * 4 + di][r];
      acc[di][0] += pv.x * wk; acc[di][1] += pv.y * wk;
      acc[di][2] += pv.z * wk; acc[di][3] += pv.w * wk;
    }
  }
#pragma unroll
  for (int di = 0; di < 4; di++) {
    float4 o;
    o.x = softplus_f(acc[di][0]); o.y = softplus_f(acc[di][1]);
    o.z = softplus_f(acc[di][2]); o.w = softplus_f(acc[di][3]);
    *(float4*)(deltaT + (size_t)(dbase + di) * BL + tokbase + tq * 4) = o;
  }
}

// ---------------- K3 (R13 version): selective scan, fully coalesced ----------------
__global__ __launch_bounds__(256) void k_scan2(const float* __restrict__ projT,
                                               float* __restrict__ deltaT,
                                               const u16* __restrict__ xT,
                                               const float* __restrict__ cw,
                                               const float* __restrict__ cb,
                                               const float* __restrict__ alog,
                                               const float* __restrict__ dparam,
                                               const float* __restrict__ cs) {
  __shared__ float wtot[4];
  __shared__ float xcp[1088];
  __shared__ float uvl[1088];
  __shared__ float dlp[1088];

  int t = threadIdx.x;
  int cidx = ((blockIdx.x & 7) << 9) | (blockIdx.x >> 3);   // (b,d)
  int b = cidx >> 11;
  int d = cidx & (DDIM - 1);
  int wv = t >> 6, lane = t & 63;

  float4 cwv = *(const float4*)(cw + d * 4);
  float cbv = cb[d];
  float Dp = dparam[d];
  int colbase = b << 10;
  int tok0 = t << 2;
  float* drow = deltaT + (size_t)d * BL + colbase;

  float4 dv = *(const float4*)(drow + tok0);

  // ---- stage x row (coalesced from xT) into dlp-aliased xls ----
  float* xls = dlp;
  if (t < 3) xls[t] = 0.f;
  {
    ushort4 xv = ((const ushort4*)(xT + (size_t)d * 2048 + colbase))[t];
    xls[3 + tok0 + 0] = bf2f(xv.x);
    xls[3 + tok0 + 1] = bf2f(xv.y);
    xls[3 + tok0 + 2] = bf2f(xv.z);
    xls[3 + tok0 + 3] = bf2f(xv.w);
  }
  __syncthreads();                       // B1

#pragma unroll
  for (int i = 0; i < 4; i++) {
    int tok = tok0 + i;
    float xc = silu_f(cbv + cwv.x * xls[tok] + cwv.y * xls[tok + 1] +
                      cwv.z * xls[tok + 2] + cwv.w * xls[tok + 3]);
    xcp[((tok >> 4) * 17) + (tok & 15)] = xc;
  }
  float d0 = dv.x, d1 = dv.y, d2 = dv.z, d3 = dv.w;
  uvl[((tok0 >> 4) * 17) + (tok0 & 15)]             = d0;
  uvl[(((tok0 + 1) >> 4) * 17) + ((tok0 + 1) & 15)] = d1;
  uvl[(((tok0 + 2) >> 4) * 17) + ((tok0 + 2) & 15)] = d2;
  uvl[(((tok0 + 3) >> 4) * 17) + ((tok0 + 3) & 15)] = d3;
  float c0 = d0, c1 = c0 + d1, c2 = c1 + d2, c3 = c2 + d3;
  float sc = c3;
#pragma unroll
  for (int off = 1; off < 64; off <<= 1) {
    float u = __shfl_up(sc, off);
    if (lane >= off) sc += u;
  }
  if (lane == 63) wtot[wv] = sc;
  __syncthreads();                       // B2
  {
    float base = sc - c3;
#pragma unroll
    for (int i = 0; i < 3; i++) if (i < wv) base += wtot[i];
    dlp[((tok0 >> 4) * 17) + (tok0 & 15)]             = base + c0;
    dlp[(((tok0 + 1) >> 4) * 17) + ((tok0 + 1) & 15)] = base + c1;
    dlp[(((tok0 + 2) >> 4) * 17) + ((tok0 + 2) & 15)] = base + c2;
    dlp[(((tok0 + 3) >> 4) * 17) + ((tok0 + 3) & 15)] = base + c3;
  }
#pragma unroll
  for (int i = 0; i < 4; i++) {
    int tok = tok0 + i;
    int p = ((tok >> 4) * 17) + (tok & 15);
    uvl[p] = uvl[p] * xcp[p];
  }
  __syncthreads();                       // B3

  int pb = lane * 17;
  float y[16];
#pragma unroll
  for (int i = 0; i < 16; i++) y[i] = 0.f;
  float Dprev = (lane == 0) ? 0.f : dlp[pb - 2];

#pragma unroll 1
  for (int r = 0; r < 4; r++) {
    int n = (wv << 2) + r;
    float An = -__expf(alog[d * NST + n]);
    float st = cs[(size_t)(b * DDIM + d) * NST + n];
    const float* pB = projT + (size_t)(64 + n) * BL + colbase + (lane << 4);
    const float* pC = pB + (size_t)16 * BL;
    float Pp = __expf(An * Dprev);
    float sl = 0.f;
#pragma unroll
    for (int c = 0; c < 4; c++) {
      float4 bv = *(const float4*)(pB + c * 4);
      float4 cv = *(const float4*)(pC + c * 4);
      float bvs[4] = {bv.x, bv.y, bv.z, bv.w};
      float cvs[4] = {cv.x, cv.y, cv.z, cv.w};
#pragma unroll
      for (int j = 0; j < 4; j++) {
        int i = c * 4 + j;
        float P = __expf(An * dlp[pb + i]);
        float w = uvl[pb + i] * bvs[j] * __builtin_amdgcn_rcpf(fmaxf(Pp, 1e-10f));
        sl += w;
        y[i] += (sl * Pp + st * P) * cvs[j];
        Pp = P;
      }
    }
    float s2 = sl;
#pragma unroll
    for (int off = 1; off < 64; off <<= 1) {
      float u = __shfl_up(s2, off);
      if (lane >= off) s2 += u;
    }
    float Soff = s2 - sl;
#pragma unroll
    for (int c = 0; c < 4; c++) {
      float4 cv = *(const float4*)(pC + c * 4);
      float cvs[4] = {cv.x, cv.y, cv.z, cv.w};
#pragma unroll
      for (int j = 0; j < 4; j++) {
        int i = c * 4 + j;
        float dlm = (i == 0) ? Dprev : dlp[pb + i - 1];
        y[i] += Soff * __expf(An * dlm) * cvs[j];
      }
    }
  }
  __syncthreads();                       // B4
  if (wv == 2) {
#pragma unroll
    for (int i = 0; i < 16; i++) uvl[pb + i] = y[i];
  } else if (wv == 3) {
#pragma unroll
    for (int i = 0; i < 16; i++) dlp[pb + i] = y[i];
  }
  __syncthreads();                       // B5
  if (wv == 0) {
#pragma unroll
    for (int i = 0; i < 16; i++) uvl[pb + i] += y[i];
  } else if (wv == 1) {
#pragma unroll
    for (int i = 0; i < 16; i++) dlp[pb + i] += y[i];
  }
  __syncthreads();                       // B6
  // ---- un-gated y (f32) -> own deltaT slice, coalesced float4 ----
  {
    float4 yo;
    int p0 = ((tok0 >> 4) * 17) + (tok0 & 15);
    int p1 = (((tok0 + 1) >> 4) * 17) + ((tok0 + 1) & 15);
    int p2 = (((tok0 + 2) >> 4) * 17) + ((tok0 + 2) & 15);
    int p3 = (((tok0 + 3) >> 4) * 17) + ((tok0 + 3) & 15);
    yo.x = uvl[p0] + dlp[p0] + xcp[p0] * Dp;
    yo.y = uvl[p1] + dlp[p1] + xcp[p1] * Dp;
    yo.z = uvl[p2] + dlp[p2] + xcp[p2] * Dp;
    yo.w = uvl[p3] + dlp[p3] + xcp[p3] * Dp;
    *(float4*)(drow + tok0) = yo;
  }
}

// ---------------- K3b: gate + transpose: yb[tok][d] = bf16(yT[d][tok] * silu(g[tok][d])) ----
__global__ __launch_bounds__(256) void k_gate(const float* __restrict__ yT,
                                              const u16* __restrict__ xgb,
                                              u16* __restrict__ yb) {
  __shared__ float tile[64 * 65];
  int dt = blockIdx.x & 31;         // d-tile (64 d)
  int tt = blockIdx.x >> 5;         // tok-tile (64 tok)
  int gtok0 = tt << 6;
  int b = gtok0 >> 10, l0 = gtok0 & 1023;
  int d0 = dt << 6;
  int t = threadIdx.x;
  // load yT tile [64 d][64 tok], coalesced rows
#pragma unroll
  for (int i = 0; i < 16; i++) {
    int idx = t + i * 256;
    int r = idx >> 6, c = idx & 63;
    tile[r * 65 + c] = yT[(size_t)(d0 + r) * BL + gtok0 + c];
  }
  __syncthreads();
  // write token-major with gate: rows = tokens, coalesced gate read + yb write
#pragma unroll
  for (int i = 0; i < 16; i++) {
    int idx = t + i * 256;
    int tr = idx >> 6, dc = idx & 63;
    float g = bf2f(xgb[(size_t)(b * XR + 3 + l0 + tr) * 4096 + 2048 + d0 + dc]);
    float yv = tile[dc * 65 + tr];
    yb[(size_t)(gtok0 + tr) * DDIM + d0 + dc] = f2bf(yv * silu_f(g));
  }
}

extern "C" void kernel_launch(void* const* d_in, const int* in_sizes, int n_in,
                              void* d_out, int out_size, void* d_ws, size_t ws_size,
                              hipStream_t stream) {
  const float* inp    = (const float*)d_in[0];
  const float* cstate = (const float*)d_in[1];
  const float* norm_w = (const float*)d_in[2];
  const float* w1     = (const float*)d_in[3];
  const float* b1     = (const float*)d_in[4];
  const float* convw  = (const float*)d_in[5];
  const float* convb  = (const float*)d_in[6];
  const float* xpw    = (const float*)d_in[7];
  const float* xpb    = (const float*)d_in[8];
  const float* dtw    = (const float*)d_in[9];
  const float* dtb    = (const float*)d_in[10];
  const float* alog   = (const float*)d_in[11];
  const float* dparam = (const float*)d_in[12];
  const float* wo     = (const float*)d_in[13];
  const float* bo     = (const float*)d_in[14];
  float* out = (float*)d_out;

  // workspace layout (ws >= 56,156,160 B confirmed R6/R8/R10/R12/R13/R15)
  char* wsb = (char*)d_ws;
  u16*   w1b    = (u16*)(wsb + 0);            //  8,388,608 B  [4096][1024] bf16 (dead after gemm1b)
  u16*   xTbuf  = w1b;                        //  8,388,608 B  xT [2048 d][2048 tok] bf16 (after gemm1b)
  u16*   wob    = (u16*)(wsb + 8388608);      //  4,194,304 B  [1024][2048] bf16
  u16*   whb    = (u16*)(wsb + 12591104);     //    393,216 B  xpw hi bf16 [96][2048]
  u16*   wlb    = (u16*)(wsb + 12984320);     //    393,216 B  xpw lo bf16 [96][2048]
  float* projT  = (float*)(wsb + 13377536);   //    786,432 B  [96][2048] f32
  u16*   xgb    = (u16*)(wsb + 14163968);     // 16,826,368 B  [2][1027][4096] bf16
  u16*   yb     = (u16*)(wsb + 30990336);     //  8,388,608 B  [2][1024][2048] bf16
  u16*   xnb    = yb;                         //  aliases yb (consumed before k_gate writes)
  float* deltaT = (float*)(wsb + 39378944);   // 16,777,216 B  [2048 d][2048 tok] f32
  float* pscr   = deltaT;                     //  first 11.8 MB: xproj K-partials (pre-k_delta)
  float* psplit = deltaT;                     //  16 MB: gemm2 split-K partials (post-k_gate)

  k_prep<<<8408, 256, 0, stream>>>(w1, w1b, wo, wob, xpw, whb, wlb, xgb,
                                   inp, norm_w, xnb);
  k_gemm1b<<<dim3(32, 16), 256, 0, stream>>>(xnb, w1b, b1, xgb);
  k_xT<<<1024, 256, 0, stream>>>(xgb, xTbuf);
  k_xprojT<<<512, 256, 0, stream>>>(xgb, whb, wlb, convw, convb, projT, pscr);
  k_xcomb<<<192, 256, 0, stream>>>(projT, pscr, xpb);
  k_delta<<<1024, 256, 0, stream>>>(projT, dtw, dtb, deltaT);
  k_scan2<<<2 * DDIM, 256, 0, stream>>>(projT, deltaT, xTbuf, convw, convb,
                                        alog, dparam, cstate);
  k_gate<<<1024, 256, 0, stream>>>(deltaT, xgb, yb);
  k_gemm2b<<<dim3(16, 16, 2), 256, 0, stream>>>(yb, wob, psplit);
  k_ocomb<<<2048, 256, 0, stream>>>(psplit, bo, inp, out);
}

// Round 17
// 253.710 us; speedup vs baseline: 1.0469x; 1.0003x over previous
//
#include <hip/hip_runtime.h>
#include <stdint.h>

#define LSEQ 1024
#define HDIM 1024
#define DDIM 2048
#define BL 2048
#define NST 16
#define XR 1027          // 3 halo rows (zeroed in k_prep) + 1024 tokens

typedef unsigned short u16;
typedef __attribute__((ext_vector_type(8))) short bf16x8;
typedef __attribute__((ext_vector_type(4))) float f32x4;

// silu via v_rcp (1-ulp rcp; output tolerance is bf16-dominated)
static __device__ __forceinline__ float silu_f(float v) {
  return v * __builtin_amdgcn_rcpf(1.f + __expf(-v));
}
static __device__ __forceinline__ float bf2f(u16 u) {
  union { float f; unsigned int i; } c; c.i = ((unsigned int)u) << 16; return c.f;
}
static __device__ __forceinline__ u16 f2bf(float f) {
  union { float f; unsigned int i; } c; c.f = f;
  unsigned int r = c.i + 0x7fffu + ((c.i >> 16) & 1u);
  return (u16)(r >> 16);
}
static __device__ __forceinline__ float softplus_f(float v) {
  return (v > 20.f) ? v : __logf(1.f + __expf(v));
}

// ---------------- fused prep: castw(w1), castw(wo), castsplit(xpw), zerohalo, rmsnorm ----
__global__ __launch_bounds__(256) void k_prep(const float* __restrict__ w1,
                                              u16* __restrict__ w1b,
                                              const float* __restrict__ wo,
                                              u16* __restrict__ wob,
                                              const float* __restrict__ xpw,
                                              u16* __restrict__ whb,
                                              u16* __restrict__ wlb,
                                              u16* __restrict__ xgb,
                                              const float* __restrict__ inp,
                                              const float* __restrict__ nw,
                                              u16* __restrict__ xnb) {
  int bidx = blockIdx.x;
  int t = threadIdx.x;
  if (bidx < 4096) {
    int idx = bidx * 256 + t;
    float4 v = ((const float4*)w1)[idx];
    ushort4 o;
    o.x = f2bf(v.x); o.y = f2bf(v.y); o.z = f2bf(v.z); o.w = f2bf(v.w);
    ((ushort4*)w1b)[idx] = o;
  } else if (bidx < 6144) {
    int idx = (bidx - 4096) * 256 + t;
    float4 v = ((const float4*)wo)[idx];
    ushort4 o;
    o.x = f2bf(v.x); o.y = f2bf(v.y); o.z = f2bf(v.z); o.w = f2bf(v.w);
    ((ushort4*)wob)[idx] = o;
  } else if (bidx < 6336) {
    int idx = (bidx - 6144) * 256 + t;
    float4 v = ((const float4*)xpw)[idx];
    ushort4 h, l;
    h.x = f2bf(v.x); l.x = f2bf(v.x - bf2f(h.x));
    h.y = f2bf(v.y); l.y = f2bf(v.y - bf2f(h.y));
    h.z = f2bf(v.z); l.z = f2bf(v.z - bf2f(h.z));
    h.w = f2bf(v.w); l.w = f2bf(v.w - bf2f(h.w));
    ((ushort4*)whb)[idx] = h;
    ((ushort4*)wlb)[idx] = l;
  } else if (bidx < 6360) {
    int idx = (bidx - 6336) * 256 + t;      // 6144 ushort4: 2 b x 3 rows x 1024
    int b = idx / 3072;
    int r = idx - b * 3072;
    ushort4 z4 = {0, 0, 0, 0};
    ((ushort4*)(xgb + (size_t)b * XR * 4096))[r] = z4;
  } else {
    // rmsnorm + normalize -> xnb bf16 [2048][1024]
    int row = bidx - 6360;
    float4 xv = *(const float4*)(inp + (size_t)row * HDIM + t * 4);
    float ss = xv.x * xv.x + xv.y * xv.y + xv.z * xv.z + xv.w * xv.w;
    for (int off = 32; off > 0; off >>= 1) ss += __shfl_down(ss, off);
    __shared__ float red[4];
    if ((t & 63) == 0) red[t >> 6] = ss;
    __syncthreads();
    float tot = red[0] + red[1] + red[2] + red[3];
    float scale = rsqrtf(tot * (1.f / HDIM) + 1e-6f);
    float4 nv = *(const float4*)(nw + t * 4);
    ushort4 o;
    o.x = f2bf(xv.x * scale * nv.x); o.y = f2bf(xv.y * scale * nv.y);
    o.z = f2bf(xv.z * scale * nv.z); o.w = f2bf(xv.w * scale * nv.w);
    ((ushort4*)xnb)[row * 256 + t] = o;
  }
}

// ---------------- K1: in_proj GEMM, 128x128 tile, global_load_lds staging ----------------
__global__ __launch_bounds__(256) void k_gemm1b(const u16* __restrict__ A,
                                                const u16* __restrict__ W,
                                                const float* __restrict__ bias,
                                                u16* __restrict__ xgb) {
  __shared__ u16 Asm[128 * 32];
  __shared__ u16 Wsm[128 * 32];
  int t = threadIdx.x;
  int m0 = blockIdx.y * 128, n0 = blockIdx.x * 128;
  int w = t >> 6, lane = t & 63;
  int wr = w >> 1, wc = w & 1;
  int quad = lane >> 4, mr = lane & 15;
  int srow = (w << 5) + (lane >> 2);       // staging row for load 0 (load 1: +16)
  int scol = (lane & 3) * 8;               // u16 offset within 32-u16 row
  const u16* Ag0 = A + (size_t)(m0 + srow) * HDIM + scol;
  const u16* Ag1 = Ag0 + (size_t)16 * HDIM;
  const u16* Wg0 = W + (size_t)(n0 + srow) * HDIM + scol;
  const u16* Wg1 = Wg0 + (size_t)16 * HDIM;
  u16* ldsA0 = &Asm[(w << 5) * 32];
  u16* ldsA1 = &Asm[((w << 5) + 16) * 32];
  u16* ldsW0 = &Wsm[(w << 5) * 32];
  u16* ldsW1 = &Wsm[((w << 5) + 16) * 32];
  f32x4 z = {0.f, 0.f, 0.f, 0.f};
  f32x4 acc[4][4] = {{z, z, z, z}, {z, z, z, z}, {z, z, z, z}, {z, z, z, z}};
  const u16* arp = &Asm[(wr * 64 + mr) * 32 + quad * 8];
  const u16* brp = &Wsm[(wc * 64 + mr) * 32 + quad * 8];
  for (int k0 = 0; k0 < HDIM; k0 += 32) {
    __syncthreads();                       // prev-iter fragment reads complete
    __builtin_amdgcn_global_load_lds(Ag0 + k0, ldsA0, 16, 0, 0);
    __builtin_amdgcn_global_load_lds(Ag1 + k0, ldsA1, 16, 0, 0);
    __builtin_amdgcn_global_load_lds(Wg0 + k0, ldsW0, 16, 0, 0);
    __builtin_amdgcn_global_load_lds(Wg1 + k0, ldsW1, 16, 0, 0);
    __syncthreads();                       // loads landed (compiler drains vmcnt)
    bf16x8 af[4], bf[4];
#pragma unroll
    for (int i = 0; i < 4; i++) {
      af[i] = *(const bf16x8*)(arp + i * 16 * 32);
      bf[i] = *(const bf16x8*)(brp + i * 16 * 32);
    }
#pragma unroll
    for (int mi = 0; mi < 4; mi++)
#pragma unroll
      for (int ni = 0; ni < 4; ni++)
        acc[mi][ni] = __builtin_amdgcn_mfma_f32_16x16x32_bf16(af[mi], bf[ni],
                                                              acc[mi][ni], 0, 0, 0);
  }
#pragma unroll
  for (int ni = 0; ni < 4; ni++) {
    int col = n0 + wc * 64 + ni * 16 + mr;
    float bv = bias[col];
#pragma unroll
    for (int mi = 0; mi < 4; mi++) {
#pragma unroll
      for (int rr2 = 0; rr2 < 4; rr2++) {
        int rr = m0 + wr * 64 + mi * 16 + quad * 4 + rr2;
        int row = (rr >> 10) * XR + 3 + (rr & 1023);
        xgb[(size_t)row * 4096 + col] = f2bf(acc[mi][ni][rr2] + bv);
      }
    }
  }
}

// ---------------- K1b: transpose x-half of xgb -> xT[2048 d][2048 tok] (bf16) ----------------
__global__ __launch_bounds__(256) void k_xT(const u16* __restrict__ xgb,
                                            u16* __restrict__ xT) {
  __shared__ u16 tile[64][66];      // row stride 66 u16 = 33 dwords (odd -> conflict-free cols)
  int dt = blockIdx.x & 31;         // d-tile (64 d)
  int tt = blockIdx.x >> 5;         // tok-tile (64 tok)
  int gtok0 = tt << 6;
  int b = gtok0 >> 10, l0 = gtok0 & 1023;
  int d0 = dt << 6;
  int t = threadIdx.x;
  const u16* src = xgb + (size_t)(b * XR + 3 + l0) * 4096 + d0;
#pragma unroll
  for (int i = 0; i < 8; i++) {
    int idx = t + i * 256;          // 0..2047
    int row = idx >> 5, uc = idx & 31;
    unsigned int v = *(const unsigned int*)(src + (size_t)row * 4096 + uc * 2);
    tile[row][uc * 2]     = (u16)(v & 0xffffu);
    tile[row][uc * 2 + 1] = (u16)(v >> 16);
  }
  __syncthreads();
#pragma unroll
  for (int i = 0; i < 8; i++) {
    int idx = t + i * 256;
    int r = idx >> 5, c2 = idx & 31;          // d-row r, token pair c2
    unsigned int lo = tile[c2 * 2][r];
    unsigned int hi = tile[c2 * 2 + 1][r];
    *(unsigned int*)(xT + (size_t)(d0 + r) * 2048 + gtok0 + c2 * 2) = lo | (hi << 16);
  }
}

// ---------------- K4: out_proj GEMM, 128x64 tile, split-K x2, gll staging ----------------
__global__ __launch_bounds__(256) void k_gemm2b(const u16* __restrict__ A,
                                                const u16* __restrict__ W,
                                                float* __restrict__ psplit) {
  __shared__ u16 Asm[128 * 32];
  __shared__ u16 Wsm[64 * 32];
  int t = threadIdx.x;
  int m0 = blockIdx.y * 128, n0 = blockIdx.x * 64;
  int kstart = blockIdx.z << 10;
  float* outp = psplit + (size_t)blockIdx.z * 2048 * 1024;
  int w = t >> 6, lane = t & 63;
  int wr = w >> 1, wc = w & 1;
  int quad = lane >> 4, mr = lane & 15;
  int srowA = (w << 5) + (lane >> 2);      // A staging rows (2 loads: +16)
  int srowW = (w << 4) + (lane >> 2);      // W staging rows (1 load)
  int scol = (lane & 3) * 8;
  const u16* Ag0 = A + (size_t)(m0 + srowA) * DDIM + kstart + scol;
  const u16* Ag1 = Ag0 + (size_t)16 * DDIM;
  const u16* Wg0 = W + (size_t)(n0 + srowW) * DDIM + kstart + scol;
  u16* ldsA0 = &Asm[(w << 5) * 32];
  u16* ldsA1 = &Asm[((w << 5) + 16) * 32];
  u16* ldsW0 = &Wsm[(w << 4) * 32];
  f32x4 z = {0.f, 0.f, 0.f, 0.f};
  f32x4 acc[4][2] = {{z, z}, {z, z}, {z, z}, {z, z}};
  const u16* arp = &Asm[(wr * 64 + mr) * 32 + quad * 8];
  const u16* brp = &Wsm[(wc * 32 + mr) * 32 + quad * 8];
  for (int k0 = 0; k0 < 1024; k0 += 32) {
    __syncthreads();                       // prev-iter fragment reads complete
    __builtin_amdgcn_global_load_lds(Ag0 + k0, ldsA0, 16, 0, 0);
    __builtin_amdgcn_global_load_lds(Ag1 + k0, ldsA1, 16, 0, 0);
    __builtin_amdgcn_global_load_lds(Wg0 + k0, ldsW0, 16, 0, 0);
    __syncthreads();                       // loads landed
    bf16x8 af[4], bf[2];
#pragma unroll
    for (int i = 0; i < 4; i++) af[i] = *(const bf16x8*)(arp + i * 16 * 32);
#pragma unroll
    for (int i = 0; i < 2; i++) bf[i] = *(const bf16x8*)(brp + i * 16 * 32);
#pragma unroll
    for (int mi = 0; mi < 4; mi++)
#pragma unroll
      for (int ni = 0; ni < 2; ni++)
        acc[mi][ni] = __builtin_amdgcn_mfma_f32_16x16x32_bf16(af[mi], bf[ni],
                                                              acc[mi][ni], 0, 0, 0);
  }
#pragma unroll
  for (int ni = 0; ni < 2; ni++) {
    int col = n0 + wc * 32 + ni * 16 + mr;
#pragma unroll
    for (int mi = 0; mi < 4; mi++) {
#pragma unroll
      for (int rr2 = 0; rr2 < 4; rr2++) {
        int row = m0 + wr * 64 + mi * 16 + quad * 4 + rr2;
        outp[(size_t)row * 1024 + col] = acc[mi][ni][rr2];
      }
    }
  }
}

// ---------------- K4b: combine split-K partials + bias + residual -> out ----------------
__global__ __launch_bounds__(256) void k_ocomb(const float* __restrict__ psplit,
                                               const float* __restrict__ bias,
                                               const float* __restrict__ resid,
                                               float* __restrict__ out) {
  int idx = blockIdx.x * 256 + threadIdx.x;   // float4 over [2048][1024]
  int colf = idx & 255;
  float4 a = ((const float4*)psplit)[idx];
  float4 b2 = ((const float4*)(psplit + 2048 * 1024))[idx];
  float4 rv = ((const float4*)resid)[idx];
  float4 bv = *(const float4*)(bias + colf * 4);
  float4 o;
  o.x = a.x + b2.x + bv.x + rv.x;
  o.y = a.y + b2.y + bv.y + rv.y;
  o.z = a.z + b2.z + bv.z + rv.z;
  o.w = a.w + b2.w + bv.w + rv.w;
  ((float4*)out)[idx] = o;
}

// ---------------- K2 v3: fused conv+silu + x_proj GEMM -> projT, 16 K-partitions ----
__global__ __launch_bounds__(256) void k_xprojT(const u16* __restrict__ xgb,
                                                const u16* __restrict__ whb,
                                                const u16* __restrict__ wlb,
                                                const float* __restrict__ cw,
                                                const float* __restrict__ cb,
                                                float* __restrict__ projT,
                                                float* __restrict__ pscr) {
  __shared__ u16 Xst[67 * 40];
  __shared__ u16 XH[64 * 40];
  __shared__ u16 XL[64 * 40];
  __shared__ u16 WH[96 * 40];
  __shared__ u16 WL[96 * 40];
  int t = threadIdx.x;
  int tt = blockIdx.x & 31, ks = blockIdx.x >> 5;
  int tokbase = tt << 6;
  int b = tokbase >> 10, l0 = tokbase & 1023;
  int kbase = ks << 7;
  const u16* xbase = xgb + (size_t)(b * XR + l0) * 4096;
  float* outp = (ks == 0) ? projT : (pscr + (size_t)(ks - 1) * 196608);
  int dlane = t & 31, tokg = t >> 5;
  int wvq = t >> 6, lane = t & 63;
  int quad = lane >> 4, mr = lane & 15;
  f32x4 z = {0.f, 0.f, 0.f, 0.f};
  f32x4 acc[6] = {z, z, z, z, z, z};

  for (int it = 0; it < 4; it++) {
    int kc = kbase + (it << 5);
    for (int idx = t; idx < 268; idx += 256) {
      int r = idx >> 2, p = idx & 3;
      uint4 v = *(const uint4*)(xbase + (size_t)r * 4096 + kc + p * 8);
      *(uint4*)(&Xst[r * 40 + p * 8]) = v;
    }
    for (int idx = t; idx < 384; idx += 256) {
      int r = idx >> 2, p = idx & 3;
      *(uint4*)(&WH[r * 40 + p * 8]) = *(const uint4*)(whb + (size_t)r * 2048 + kc + p * 8);
      *(uint4*)(&WL[r * 40 + p * 8]) = *(const uint4*)(wlb + (size_t)r * 2048 + kc + p * 8);
    }
    __syncthreads();
    {
      int d = kc + dlane;
      float4 cwv = *(const float4*)(cw + d * 4);
      float cbv = cb[d];
      float xr[11];
#pragma unroll
      for (int j = 0; j < 11; j++) xr[j] = bf2f(Xst[(tokg * 8 + j) * 40 + dlane]);
#pragma unroll
      for (int jj = 0; jj < 8; jj++) {
        float xc = silu_f(cbv + cwv.x * xr[jj] + cwv.y * xr[jj + 1] +
                          cwv.z * xr[jj + 2] + cwv.w * xr[jj + 3]);
        u16 h = f2bf(xc);
        u16 l = f2bf(xc - bf2f(h));
        XH[(tokg * 8 + jj) * 40 + dlane] = h;
        XL[(tokg * 8 + jj) * 40 + dlane] = l;
      }
    }
    __syncthreads();
    bf16x8 xh = *(const bf16x8*)(&XH[(wvq * 16 + mr) * 40 + quad * 8]);
    bf16x8 xl = *(const bf16x8*)(&XL[(wvq * 16 + mr) * 40 + quad * 8]);
#pragma unroll
    for (int mi = 0; mi < 6; mi++) {
      bf16x8 wh = *(const bf16x8*)(&WH[(mi * 16 + mr) * 40 + quad * 8]);
      bf16x8 wl = *(const bf16x8*)(&WL[(mi * 16 + mr) * 40 + quad * 8]);
      acc[mi] = __builtin_amdgcn_mfma_f32_16x16x32_bf16(wh, xh, acc[mi], 0, 0, 0);
      acc[mi] = __builtin_amdgcn_mfma_f32_16x16x32_bf16(wh, xl, acc[mi], 0, 0, 0);
      acc[mi] = __builtin_amdgcn_mfma_f32_16x16x32_bf16(wl, xh, acc[mi], 0, 0, 0);
    }
    __syncthreads();
  }
#pragma unroll
  for (int mi = 0; mi < 6; mi++) {
#pragma unroll
    for (int rr = 0; rr < 4; rr++) {
      int o = mi * 16 + quad * 4 + rr;
      outp[(size_t)o * BL + tokbase + wvq * 16 + mr] = acc[mi][rr];
    }
  }
}

// ---------------- K2d: combine 16 K-partials + bias into projT ----------------
__global__ __launch_bounds__(256) void k_xcomb(float* __restrict__ projT,
                                               const float* __restrict__ scr,
                                               const float* __restrict__ xpb) {
  int idx = blockIdx.x * 256 + threadIdx.x;
  int o = idx >> 9;
  float4 a = ((const float4*)projT)[idx];
  float bv = xpb[o];
  float sx = bv, sy = bv, sz = bv, sw = bv;
#pragma unroll
  for (int p = 0; p < 15; p++) {
    float4 s = ((const float4*)(scr + (size_t)p * 196608))[idx];
    sx += s.x; sy += s.y; sz += s.z; sw += s.w;
  }
  a.x += sx; a.y += sy; a.z += sz; a.w += sw;
  ((float4*)projT)[idx] = a;
}

// ---------------- K2c: delta GEMM: deltaT[2048 d][2048 tok] = softplus(dtw.projT + dtb) ----
__global__ __launch_bounds__(256) void k_delta(const float* __restrict__ projT,
                                               const float* __restrict__ dtw,
                                               const float* __restrict__ dtb,
                                               float* __restrict__ deltaT) {
  __shared__ float dw_s[16][64];
  int t = threadIdx.x;
  int d0 = (blockIdx.x >> 3) * 16;
  int tokbase = (blockIdx.x & 7) * 256;
  {
    const float* src = dtw + (size_t)d0 * 64;
#pragma unroll
    for (int i = 0; i < 4; i++) {
      int idx = t + i * 256;
      dw_s[idx >> 6][idx & 63] = src[idx];
    }
  }
  __syncthreads();
  int tq = t & 63, dq = t >> 6;
  const float* pr = projT + tokbase + tq * 4;
  int dbase = d0 + dq * 4;
  float acc[4][4];
#pragma unroll
  for (int di = 0; di < 4; di++) {
    float bv = dtb[dbase + di];
    acc[di][0] = bv; acc[di][1] = bv; acc[di][2] = bv; acc[di][3] = bv;
  }
#pragma unroll 8
  for (int r = 0; r < 64; r++) {
    float4 pv = *(const float4*)(pr + (size_t)r * BL);
#pragma unroll
    for (int di = 0; di < 4; di++) {
      float wk = dw_s[dq * 4 + di][r];
      acc[di][0] += pv.x * wk; acc[di][1] += pv.y * wk;
      acc[di][2] += pv.z * wk; acc[di][3] += pv.w * wk;
    }
  }
#pragma unroll
  for (int di = 0; di < 4; di++) {
    float4 o;
    o.x = softplus_f(acc[di][0]); o.y = softplus_f(acc[di][1]);
    o.z = softplus_f(acc[di][2]); o.w = softplus_f(acc[di][3]);
    *(float4*)(deltaT + (size_t)(dbase + di) * BL + tokbase + tq * 4) = o;
  }
}

// ---------------- K3 v6: selective scan; conv via registers+shfl (no xls LDS) ----------------
// x staged straight into registers from xT (ushort4); conv halo x[4t-3..4t-1]
// comes from thread t-1 via __shfl_up (wave-boundary via 12-float LDS, wave0
// lane0 = 0 matching the reference zero-pad).  Removes the stride-4 8-way
// bank-conflicted xls writes + conv reads (SQ_LDS_BANK_CONFLICT 2.33M).
// Conv FMA order identical -> xc bitwise unchanged.
__global__ __launch_bounds__(256) void k_scan2(const float* __restrict__ projT,
                                               float* __restrict__ deltaT,
                                               const u16* __restrict__ xT,
                                               const float* __restrict__ cw,
                                               const float* __restrict__ cb,
                                               const float* __restrict__ alog,
                                               const float* __restrict__ dparam,
                                               const float* __restrict__ cs) {
  __shared__ float wtot[4];
  __shared__ float bnd[4][3];    // wave w's lane63 x[1..3] -> wave w+1 lane0 halo
  __shared__ float xcp[1088];
  __shared__ float uvl[1088];
  __shared__ float dlp[1088];

  int t = threadIdx.x;
  int cidx = ((blockIdx.x & 7) << 9) | (blockIdx.x >> 3);   // (b,d)
  int b = cidx >> 11;
  int d = cidx & (DDIM - 1);
  int wv = t >> 6, lane = t & 63;

  float4 cwv = *(const float4*)(cw + d * 4);
  float cbv = cb[d];
  float Dp = dparam[d];
  int colbase = b << 10;
  int tok0 = t << 2;
  float* drow = deltaT + (size_t)d * BL + colbase;

  float4 dv = *(const float4*)(drow + tok0);

  // ---- x[4t..4t+3] straight to registers ----
  float x0, x1, x2, x3;
  {
    ushort4 xv = ((const ushort4*)(xT + (size_t)d * 2048 + colbase))[t];
    x0 = bf2f(xv.x); x1 = bf2f(xv.y); x2 = bf2f(xv.z); x3 = bf2f(xv.w);
  }
  if (lane == 63) { bnd[wv][0] = x1; bnd[wv][1] = x2; bnd[wv][2] = x3; }
  __syncthreads();                       // B1: boundary handoff visible
  // halo x[4t-3..4t-1] from thread t-1 (shfl within wave; LDS across waves)
  float p1 = __shfl_up(x1, 1);
  float p2 = __shfl_up(x2, 1);
  float p3 = __shfl_up(x3, 1);
  if (lane == 0) {
    if (wv == 0) { p1 = 0.f; p2 = 0.f; p3 = 0.f; }
    else { p1 = bnd[wv - 1][0]; p2 = bnd[wv - 1][1]; p3 = bnd[wv - 1][2]; }
  }
  // ---- conv + silu -> xcp (FMA order identical to reference path) ----
  {
    float xc0 = silu_f(cbv + cwv.x * p1 + cwv.y * p2 + cwv.z * p3 + cwv.w * x0);
    float xc1 = silu_f(cbv + cwv.x * p2 + cwv.y * p3 + cwv.z * x0 + cwv.w * x1);
    float xc2 = silu_f(cbv + cwv.x * p3 + cwv.y * x0 + cwv.z * x1 + cwv.w * x2);
    float xc3 = silu_f(cbv + cwv.x * x0 + cwv.y * x1 + cwv.z * x2 + cwv.w * x3);
    xcp[((tok0 >> 4) * 17) + (tok0 & 15)]             = xc0;
    xcp[(((tok0 + 1) >> 4) * 17) + ((tok0 + 1) & 15)] = xc1;
    xcp[(((tok0 + 2) >> 4) * 17) + ((tok0 + 2) & 15)] = xc2;
    xcp[(((tok0 + 3) >> 4) * 17) + ((tok0 + 3) & 15)] = xc3;
  }
  float d0 = dv.x, d1 = dv.y, d2 = dv.z, d3 = dv.w;
  uvl[((tok0 >> 4) * 17) + (tok0 & 15)]             = d0;
  uvl[(((tok0 + 1) >> 4) * 17) + ((tok0 + 1) & 15)] = d1;
  uvl[(((tok0 + 2) >> 4) * 17) + ((tok0 + 2) & 15)] = d2;
  uvl[(((tok0 + 3) >> 4) * 17) + ((tok0 + 3) & 15)] = d3;
  float c0 = d0, c1 = c0 + d1, c2 = c1 + d2, c3 = c2 + d3;
  float sc = c3;
#pragma unroll
  for (int off = 1; off < 64; off <<= 1) {
    float u = __shfl_up(sc, off);
    if (lane >= off) sc += u;
  }
  if (lane == 63) wtot[wv] = sc;
  __syncthreads();                       // B2: wtot visible
  {
    float base = sc - c3;
#pragma unroll
    for (int i = 0; i < 3; i++) if (i < wv) base += wtot[i];
    dlp[((tok0 >> 4) * 17) + (tok0 & 15)]             = base + c0;
    dlp[(((tok0 + 1) >> 4) * 17) + ((tok0 + 1) & 15)] = base + c1;
    dlp[(((tok0 + 2) >> 4) * 17) + ((tok0 + 2) & 15)] = base + c2;
    dlp[(((tok0 + 3) >> 4) * 17) + ((tok0 + 3) & 15)] = base + c3;
  }
#pragma unroll
  for (int i = 0; i < 4; i++) {
    int tok = tok0 + i;
    int p = ((tok >> 4) * 17) + (tok & 15);
    uvl[p] = uvl[p] * xcp[p];
  }
  __syncthreads();                       // B3: Dl + uv visible

  int pb = lane * 17;
  float y[16];
#pragma unroll
  for (int i = 0; i < 16; i++) y[i] = 0.f;
  float Dprev = (lane == 0) ? 0.f : dlp[pb - 2];

#pragma unroll 1
  for (int r = 0; r < 4; r++) {
    int n = (wv << 2) + r;
    float An = -__expf(alog[d * NST + n]);
    float st = cs[(size_t)(b * DDIM + d) * NST + n];
    const float* pB = projT + (size_t)(64 + n) * BL + colbase + (lane << 4);
    const float* pC = pB + (size_t)16 * BL;
    float Pp = __expf(An * Dprev);
    float sl = 0.f;
#pragma unroll
    for (int c = 0; c < 4; c++) {
      float4 bv = *(const float4*)(pB + c * 4);
      float4 cv = *(const float4*)(pC + c * 4);
      float bvs[4] = {bv.x, bv.y, bv.z, bv.w};
      float cvs[4] = {cv.x, cv.y, cv.z, cv.w};
#pragma unroll
      for (int j = 0; j < 4; j++) {
        int i = c * 4 + j;
        float P = __expf(An * dlp[pb + i]);
        float w = uvl[pb + i] * bvs[j] * __builtin_amdgcn_rcpf(fmaxf(Pp, 1e-10f));
        sl += w;
        y[i] += (sl * Pp + st * P) * cvs[j];
        Pp = P;
      }
    }
    float s2 = sl;
#pragma unroll
    for (int off = 1; off < 64; off <<= 1) {
      float u = __shfl_up(s2, off);
      if (lane >= off) s2 += u;
    }
    float Soff = s2 - sl;
#pragma unroll
    for (int c = 0; c < 4; c++) {
      float4 cv = *(const float4*)(pC + c * 4);
      float cvs[4] = {cv.x, cv.y, cv.z, cv.w};
#pragma unroll
      for (int j = 0; j < 4; j++) {
        int i = c * 4 + j;
        float dlm = (i == 0) ? Dprev : dlp[pb + i - 1];
        y[i] += Soff * __expf(An * dlm) * cvs[j];
      }
    }
  }
  __syncthreads();                       // B4
  if (wv == 2) {
#pragma unroll
    for (int i = 0; i < 16; i++) uvl[pb + i] = y[i];
  } else if (wv == 3) {
#pragma unroll
    for (int i = 0; i < 16; i++) dlp[pb + i] = y[i];
  }
  __syncthreads();                       // B5
  if (wv == 0) {
#pragma unroll
    for (int i = 0; i < 16; i++) uvl[pb + i] += y[i];
  } else if (wv == 1) {
#pragma unroll
    for (int i = 0; i < 16; i++) dlp[pb + i] += y[i];
  }
  __syncthreads();                       // B6
  // ---- un-gated y (f32) -> own deltaT slice, coalesced float4 ----
  {
    float4 yo;
    int p0 = ((tok0 >> 4) * 17) + (tok0 & 15);
    int p1i = (((tok0 + 1) >> 4) * 17) + ((tok0 + 1) & 15);
    int p2i = (((tok0 + 2) >> 4) * 17) + ((tok0 + 2) & 15);
    int p3i = (((tok0 + 3) >> 4) * 17) + ((tok0 + 3) & 15);
    yo.x = uvl[p0] + dlp[p0] + xcp[p0] * Dp;
    yo.y = uvl[p1i] + dlp[p1i] + xcp[p1i] * Dp;
    yo.z = uvl[p2i] + dlp[p2i] + xcp[p2i] * Dp;
    yo.w = uvl[p3i] + dlp[p3i] + xcp[p3i] * Dp;
    *(float4*)(drow + tok0) = yo;
  }
}

// ---------------- K3b: gate + transpose: yb[tok][d] = bf16(yT[d][tok] * silu(g[tok][d])) ----
__global__ __launch_bounds__(256) void k_gate(const float* __restrict__ yT,
                                              const u16* __restrict__ xgb,
                                              u16* __restrict__ yb) {
  __shared__ float tile[64 * 65];
  int dt = blockIdx.x & 31;         // d-tile (64 d)
  int tt = blockIdx.x >> 5;         // tok-tile (64 tok)
  int gtok0 = tt << 6;
  int b = gtok0 >> 10, l0 = gtok0 & 1023;
  int d0 = dt << 6;
  int t = threadIdx.x;
  // load yT tile [64 d][64 tok], coalesced rows
#pragma unroll
  for (int i = 0; i < 16; i++) {
    int idx = t + i * 256;
    int r = idx >> 6, c = idx & 63;
    tile[r * 65 + c] = yT[(size_t)(d0 + r) * BL + gtok0 + c];
  }
  __syncthreads();
  // write token-major with gate: rows = tokens, coalesced gate read + yb write
#pragma unroll
  for (int i = 0; i < 16; i++) {
    int idx = t + i * 256;
    int tr = idx >> 6, dc = idx & 63;
    float g = bf2f(xgb[(size_t)(b * XR + 3 + l0 + tr) * 4096 + 2048 + d0 + dc]);
    float yv = tile[dc * 65 + tr];
    yb[(size_t)(gtok0 + tr) * DDIM + d0 + dc] = f2bf(yv * silu_f(g));
  }
}

extern "C" void kernel_launch(void* const* d_in, const int* in_sizes, int n_in,
                              void* d_out, int out_size, void* d_ws, size_t ws_size,
                              hipStream_t stream) {
  const float* inp    = (const float*)d_in[0];
  const float* cstate = (const float*)d_in[1];
  const float* norm_w = (const float*)d_in[2];
  const float* w1     = (const float*)d_in[3];
  const float* b1     = (const float*)d_in[4];
  const float* convw  = (const float*)d_in[5];
  const float* convb  = (const float*)d_in[6];
  const float* xpw    = (const float*)d_in[7];
  const float* xpb    = (const float*)d_in[8];
  const float* dtw    = (const float*)d_in[9];
  const float* dtb    = (const float*)d_in[10];
  const float* alog   = (const float*)d_in[11];
  const float* dparam = (const float*)d_in[12];
  const float* wo     = (const float*)d_in[13];
  const float* bo     = (const float*)d_in[14];
  float* out = (float*)d_out;

  // workspace layout (ws >= 56,156,160 B confirmed R6/R8/R10/R12/R13/R15/R16)
  char* wsb = (char*)d_ws;
  u16*   w1b    = (u16*)(wsb + 0);            //  8,388,608 B  [4096][1024] bf16 (dead after gemm1b)
  u16*   xTbuf  = w1b;                        //  8,388,608 B  xT [2048 d][2048 tok] bf16 (after gemm1b)
  u16*   wob    = (u16*)(wsb + 8388608);      //  4,194,304 B  [1024][2048] bf16
  u16*   whb    = (u16*)(wsb + 12591104);     //    393,216 B  xpw hi bf16 [96][2048]
  u16*   wlb    = (u16*)(wsb + 12984320);     //    393,216 B  xpw lo bf16 [96][2048]
  float* projT  = (float*)(wsb + 13377536);   //    786,432 B  [96][2048] f32
  u16*   xgb    = (u16*)(wsb + 14163968);     // 16,826,368 B  [2][1027][4096] bf16
  u16*   yb     = (u16*)(wsb + 30990336);     //  8,388,608 B  [2][1024][2048] bf16
  u16*   xnb    = yb;                         //  aliases yb (consumed before k_gate writes)
  float* deltaT = (float*)(wsb + 39378944);   // 16,777,216 B  [2048 d][2048 tok] f32
  float* pscr   = deltaT;                     //  first 11.8 MB: xproj K-partials (pre-k_delta)
  float* psplit = deltaT;                     //  16 MB: gemm2 split-K partials (post-k_gate)

  k_prep<<<8408, 256, 0, stream>>>(w1, w1b, wo, wob, xpw, whb, wlb, xgb,
                                   inp, norm_w, xnb);
  k_gemm1b<<<dim3(32, 16), 256, 0, stream>>>(xnb, w1b, b1, xgb);
  k_xT<<<1024, 256, 0, stream>>>(xgb, xTbuf);
  k_xprojT<<<512, 256, 0, stream>>>(xgb, whb, wlb, convw, convb, projT, pscr);
  k_xcomb<<<192, 256, 0, stream>>>(projT, pscr, xpb);
  k_delta<<<1024, 256, 0, stream>>>(projT, dtw, dtb, deltaT);
  k_scan2<<<2 * DDIM, 256, 0, stream>>>(projT, deltaT, xTbuf, convw, convb,
                                        alog, dparam, cstate);
  k_gate<<<1024, 256, 0, stream>>>(deltaT, xgb, yb);
  k_gemm2b<<<dim3(16, 16, 2), 256, 0, stream>>>(yb, wob, psplit);
  k_ocomb<<<2048, 256, 0, stream>>>(psplit, bo, inp, out);
}